// Round 8
// baseline (95.059 us; speedup 1.0000x reference)
//
#include <hip/hip_runtime.h>
#include <hip/hip_bf16.h>
#include <stdint.h>

#define TT 2048
#define DD 1024
#define NH 16
#define DK 64

typedef __attribute__((ext_vector_type(8))) short bf16x8;
typedef __attribute__((ext_vector_type(4))) float f32x4;
typedef __attribute__((ext_vector_type(4))) unsigned uint4v;
typedef __attribute__((ext_vector_type(8))) unsigned short u16x8;
typedef __attribute__((ext_vector_type(4))) unsigned short u16x4;

__device__ __forceinline__ unsigned short f2bf(float f) {
  union { float f; unsigned u; } x; x.f = f;
  unsigned r = (x.u + 0x7FFFu + ((x.u >> 16) & 1u)) >> 16;
  return (unsigned short)r;
}

__device__ __forceinline__ unsigned cvt2(float lo, float hi) {
  unsigned r;
  asm("v_cvt_pk_bf16_f32 %0, %1, %2" : "=v"(r) : "v"(lo), "v"(hi));
  return r;
}

__device__ __forceinline__ void gload16(const void* g, void* l) {
  __builtin_amdgcn_global_load_lds(
      (const __attribute__((address_space(1))) unsigned int*)g,
      (__attribute__((address_space(3))) unsigned int*)l, 16, 0, 0);
}

// ---------------- RoPE cos/sin table ----------------
__global__ __launch_bounds__(256) void rope_tab(const int* __restrict__ pos,
                                                float* __restrict__ cosT,
                                                float* __restrict__ sinT) {
  int idx = blockIdx.x * 256 + threadIdx.x;  // 2048*32
  int t = idx >> 5, i = idx & 31;
  float inv = exp2f((float)i * -0.41524101186092028f);  // 10000^(-i/32)
  float ang = (float)pos[t] * inv;
  cosT[idx] = cosf(ang);
  sinT[idx] = sinf(ang);
}

// stage a RxC f32 tile (row stride 1024) into bf16 LDS with XOR swizzle.
// ITERS = R*C/8/256. Each thread: 8 f32 -> cvt_pk -> ds_write_b128.
template <int ITERS>
__device__ __forceinline__ void stage_f32(const float* __restrict__ src0,
                                          char* lds, int tid) {
#pragma unroll
  for (int it = 0; it < ITERS; ++it) {
    int c = it * 256 + tid;
    int row = c >> 3;
    int col8 = (c & 7) * 8;
    const float* s = src0 + (size_t)row * DD + col8;
    f32x4 a = *(const f32x4*)s;
    f32x4 b = *(const f32x4*)(s + 4);
    uint4v pk;
    pk[0] = cvt2(a[0], a[1]);
    pk[1] = cvt2(a[2], a[3]);
    pk[2] = cvt2(b[0], b[1]);
    pk[3] = cvt2(b[2], b[3]);
    *(uint4v*)(lds + row * 128 + ((col8 * 2) ^ ((row & 7) << 4))) = pk;
  }
}

// ---------------- fused QKV projection + RoPE (f32 in, fragment-native out) --
// 128x64 tile (one head per block), 4 waves x (32 rows x 64 cols), BK=64.
//  QF[h][qw][mi][ks][lane], KF[h][kt][ks][ni][lane], VF[h][kt][ks][ni][lane]
__global__ __launch_bounds__(256) void gemm_qkv(
    const float* __restrict__ xq, const float* __restrict__ xk,
    const float* __restrict__ xv,
    const float* __restrict__ wqf, const float* __restrict__ wkf,
    const float* __restrict__ wvf,
    unsigned short* __restrict__ QF, unsigned short* __restrict__ KF,
    unsigned short* __restrict__ VF,
    const float* __restrict__ cosT, const float* __restrict__ sinT) {
  __shared__ unsigned short Ash[128 * 64];
  __shared__ unsigned short Bsh[64 * 64];
  const int z = blockIdx.z;
  const float* A = (z == 0) ? xq : (z == 1) ? xk : xv;
  const float* W = (z == 0) ? wqf : (z == 1) ? wkf : wvf;
  const int brow = blockIdx.x * 128;
  const int h = blockIdx.y;            // bcol = h*64: one head per block
  const int tid = threadIdx.x;
  const int lane = tid & 63;
  const int w = tid >> 6;
  char* AshB = (char*)Ash;
  char* BshB = (char*)Bsh;
  f32x4 acc[2][4];
#pragma unroll
  for (int mi = 0; mi < 2; ++mi)
#pragma unroll
    for (int ni = 0; ni < 4; ++ni)
#pragma unroll
      for (int r = 0; r < 4; ++r) acc[mi][ni][r] = 0.0f;

  for (int k0 = 0; k0 < DD; k0 += 64) {
    __syncthreads();
    stage_f32<4>(A + (size_t)brow * DD + k0, AshB, tid);
    stage_f32<2>(W + (size_t)h * 64 * DD + k0, BshB, tid);
    __syncthreads();
#pragma unroll
    for (int ks = 0; ks < 2; ++ks) {
      bf16x8 af[2], bfr[4];
      int colb = ks * 64 + ((lane >> 4) << 4);
#pragma unroll
      for (int mi = 0; mi < 2; ++mi) {
        int row = w * 32 + mi * 16 + (lane & 15);
        af[mi] = *(const bf16x8*)(AshB + row * 128 + (colb ^ ((row & 7) << 4)));
      }
#pragma unroll
      for (int ni = 0; ni < 4; ++ni) {
        int row = ni * 16 + (lane & 15);
        bfr[ni] = *(const bf16x8*)(BshB + row * 128 + (colb ^ ((row & 7) << 4)));
      }
#pragma unroll
      for (int mi = 0; mi < 2; ++mi)
#pragma unroll
        for (int ni = 0; ni < 4; ++ni)
          acc[mi][ni] = __builtin_amdgcn_mfma_f32_16x16x32_bf16(af[mi], bfr[ni], acc[mi][ni], 0, 0, 0);
    }
  }

  if (z == 0) {
    // Q + RoPE + scale(1/8 * log2e) -> QF fragment-native
    const float sc = 0.18033688011112042f;
#pragma unroll
    for (int mi = 0; mi < 2; ++mi) {
#pragma unroll
      for (int r = 0; r < 4; ++r) {
        int t = brow + w * 32 + mi * 16 + ((lane >> 4) << 2) + r;
        int qw_ = t >> 5, mif = (t >> 4) & 1, r16 = t & 15;
        size_t fb = (((size_t)(h * 64 + qw_) * 2 + mif) * 2) * 1024;  // bytes, ks=0
#pragma unroll
        for (int ni = 0; ni < 2; ++ni) {
          int dl = ni * 16 + (lane & 15);  // d in [0,32)
          float cv = cosT[t * 32 + dl];
          float sv = sinT[t * 32 + dl];
          float x1 = acc[mi][ni][r];
          float x2 = acc[mi][ni + 2][r];
          size_t off = fb + (size_t)(r16 + 16 * (dl >> 3)) * 16 + (dl & 7) * 2;
          *(unsigned short*)((char*)QF + off) = f2bf((x1 * cv - x2 * sv) * sc);
          *(unsigned short*)((char*)QF + off + 1024) = f2bf((x2 * cv + x1 * sv) * sc);
        }
      }
    }
  } else if (z == 1) {
    // K + RoPE -> KF fragment-native
#pragma unroll
    for (int mi = 0; mi < 2; ++mi) {
#pragma unroll
      for (int r = 0; r < 4; ++r) {
        int t = brow + w * 32 + mi * 16 + ((lane >> 4) << 2) + r;
        int kt = t >> 6, nif = (t >> 4) & 3, r16 = t & 15;
        size_t fb = (((size_t)(h * 32 + kt) * 2) * 4 + nif) * 1024;  // bytes, ks=0
#pragma unroll
        for (int ni = 0; ni < 2; ++ni) {
          int dl = ni * 16 + (lane & 15);
          float cv = cosT[t * 32 + dl];
          float sv = sinT[t * 32 + dl];
          float x1 = acc[mi][ni][r];
          float x2 = acc[mi][ni + 2][r];
          size_t off = fb + (size_t)(r16 + 16 * (dl >> 3)) * 16 + (dl & 7) * 2;
          *(unsigned short*)((char*)KF + off) = f2bf(x1 * cv - x2 * sv);
          *(unsigned short*)((char*)KF + off + 4096) = f2bf(x2 * cv + x1 * sv);  // ks=1
        }
      }
    }
  } else {
    // V -> VF fragment-native
#pragma unroll
    for (int mi = 0; mi < 2; ++mi) {
      int t0 = brow + w * 32 + mi * 16 + ((lane >> 4) << 2);
      int kt = t0 >> 6, ksf = (t0 & 63) >> 5, slot = (t0 & 31) >> 3, j0 = t0 & 7;
#pragma unroll
      for (int ni = 0; ni < 4; ++ni) {
        int dh = ni * 16 + (lane & 15);
        int lanef = (dh & 15) + 16 * slot;
        size_t off = ((((size_t)(h * 32 + kt) * 2 + ksf) * 4 + ni) * 64 + lanef) * 16 + j0 * 2;
        u16x4 pk;
#pragma unroll
        for (int r = 0; r < 4; ++r) pk[r] = f2bf(acc[mi][ni][r]);
        *(u16x4*)((char*)VF + off) = pk;
      }
    }
  }
}

// ---------------- causal flash attention (unchanged from R7) ----------------
__global__ __launch_bounds__(256, 2) void attn_fa(
    const unsigned short* __restrict__ QF, const unsigned short* __restrict__ KF,
    const unsigned short* __restrict__ VF, unsigned short* __restrict__ AO) {
  __shared__ char LB[26624];
  __shared__ float MR[4][32];
  const int tid = threadIdx.x;
  const int lane = tid & 63;
  const int w = tid >> 6;
  const int bid = blockIdx.x;
  const int xcd = bid & 7;
  const int idx = bid >> 3;          // 128 jobs per XCD
  const int h = xcd * 2 + (idx & 1); // 2 heads pinned per XCD
  const int qw = 63 - (idx >> 1);    // biggest jobs dispatch first
  const int q0w = qw * 32;
  const int NT = (qw >> 1) + 1;
  char* PshB = LB + w * 4096;
  const char* Kb = (const char*)KF + (size_t)h * 32 * 8192;  // 8KB per k-tile
  const char* Vb = (const char*)VF + (size_t)h * 32 * 8192;

  bf16x8 qf[2][2];
  {
    const char* Qb = (const char*)QF + (size_t)(h * 64 + qw) * 4096;
#pragma unroll
    for (int mi = 0; mi < 2; ++mi)
#pragma unroll
      for (int ks = 0; ks < 2; ++ks)
        qf[mi][ks] = *(const bf16x8*)(Qb + (mi * 2 + ks) * 1024 + lane * 16);
  }

  bf16x8 vone;
#pragma unroll
  for (int j = 0; j < 8; ++j) vone[j] = (short)0x3F80;  // bf16 1.0

  f32x4 accO[2][5];  // [..][4] = row-sum l (ones-column MFMA)
  float mrow[2];
#pragma unroll
  for (int mi = 0; mi < 2; ++mi) {
    mrow[mi] = -1e30f;
#pragma unroll
    for (int ni = 0; ni < 5; ++ni)
#pragma unroll
      for (int r = 0; r < 4; ++r) accO[mi][ni][r] = 0.0f;
  }

  bf16x8 kfA[2][4], kfB[2][4], vf[2][4];
  {
    int kt0 = (w < NT) ? w : 0;
    const char* p = Kb + (size_t)kt0 * 8192 + lane * 16;
#pragma unroll
    for (int ks = 0; ks < 2; ++ks)
#pragma unroll
      for (int ni = 0; ni < 4; ++ni)
        kfA[ks][ni] = *(const bf16x8*)(p + (ks * 4 + ni) * 1024);
  }

  for (int kt = w; kt < NT; kt += 4) {
    {  // V tile: coalesced; issue early, QK+softmax hides latency
      const char* p = Vb + (size_t)kt * 8192 + lane * 16;
#pragma unroll
      for (int ks = 0; ks < 2; ++ks)
#pragma unroll
        for (int ni = 0; ni < 4; ++ni)
          vf[ks][ni] = *(const bf16x8*)(p + (ks * 4 + ni) * 1024);
    }
    f32x4 s[2][4];
#pragma unroll
    for (int mi = 0; mi < 2; ++mi)
#pragma unroll
      for (int ni = 0; ni < 4; ++ni)
#pragma unroll
        for (int r = 0; r < 4; ++r) s[mi][ni][r] = 0.0f;
    // swapped: S^T[k][q] = K-frag (A) x Q-frag (B)
    __builtin_amdgcn_s_setprio(1);
#pragma unroll
    for (int ks = 0; ks < 2; ++ks)
#pragma unroll
      for (int mi = 0; mi < 2; ++mi)
#pragma unroll
        for (int ni = 0; ni < 4; ++ni)
          s[mi][ni] = __builtin_amdgcn_mfma_f32_16x16x32_bf16(kfA[ks][ni], qf[mi][ks], s[mi][ni], 0, 0, 0);
    __builtin_amdgcn_s_setprio(0);
    if (kt + 4 < NT) {  // prefetch own next K tile
      const char* p = Kb + (size_t)(kt + 4) * 8192 + lane * 16;
#pragma unroll
      for (int ks = 0; ks < 2; ++ks)
#pragma unroll
        for (int ni = 0; ni < 4; ++ni)
          kfB[ks][ni] = *(const bf16x8*)(p + (ks * 4 + ni) * 1024);
    }

    if (kt == NT - 1) {  // diagonal tile: causal mask
#pragma unroll
      for (int mi = 0; mi < 2; ++mi) {
        int qq = q0w + mi * 16 + (lane & 15);
#pragma unroll
        for (int ni = 0; ni < 4; ++ni) {
          int kb = kt * 64 + ni * 16 + ((lane >> 4) << 2);
#pragma unroll
          for (int r = 0; r < 4; ++r)
            if (kb + r > qq) s[mi][ni][r] = -1e30f;
        }
      }
    }
    float rmx[2];
#pragma unroll
    for (int mi = 0; mi < 2; ++mi) {
      f32x4 t;
#pragma unroll
      for (int r = 0; r < 4; ++r)
        t[r] = fmaxf(fmaxf(s[mi][0][r], s[mi][1][r]), fmaxf(s[mi][2][r], s[mi][3][r]));
      float mx = fmaxf(fmaxf(t[0], t[1]), fmaxf(t[2], t[3]));
      mx = fmaxf(mx, __shfl_xor(mx, 16, 64));
      mx = fmaxf(mx, __shfl_xor(mx, 32, 64));
      rmx[mi] = mx;
    }
    bool need = (rmx[0] > mrow[0] + 8.0f) || (rmx[1] > mrow[1] + 8.0f);
    if (__any(need)) {
#pragma unroll
      for (int mi = 0; mi < 2; ++mi) {
        float mn = fmaxf(mrow[mi], rmx[mi]);
        float al = exp2f(mrow[mi] - mn);
        mrow[mi] = mn;
        float ar[4];
#pragma unroll
        for (int r = 0; r < 4; ++r) ar[r] = __shfl(al, ((lane >> 4) << 2) + r, 64);
#pragma unroll
        for (int ni = 0; ni < 5; ++ni)
#pragma unroll
          for (int r = 0; r < 4; ++r) accO[mi][ni][r] *= ar[r];
      }
    }
#pragma unroll
    for (int mi = 0; mi < 2; ++mi) {
      int row = mi * 16 + (lane & 15);
      int rbase = row * 128;
      int sw = (row & 7) << 4;
#pragma unroll
      for (int ni = 0; ni < 4; ++ni) {
        unsigned u0 = __float_as_uint(exp2f(s[mi][ni][0] - mrow[mi]));
        unsigned u1 = __float_as_uint(exp2f(s[mi][ni][1] - mrow[mi]));
        unsigned u2 = __float_as_uint(exp2f(s[mi][ni][2] - mrow[mi]));
        unsigned u3 = __float_as_uint(exp2f(s[mi][ni][3] - mrow[mi]));
        uint2 pk;
        pk.x = (u0 >> 16) | (u1 & 0xFFFF0000u);
        pk.y = (u2 >> 16) | (u3 & 0xFFFF0000u);
        int cb = ni * 32 + ((lane >> 4) << 3);
        *(uint2*)(PshB + rbase + (cb ^ sw)) = pk;
      }
    }
    asm volatile("" ::: "memory");
    __builtin_amdgcn_s_setprio(1);
#pragma unroll
    for (int ks = 0; ks < 2; ++ks) {
      bf16x8 pf[2];
#pragma unroll
      for (int mi = 0; mi < 2; ++mi) {
        int row = mi * 16 + (lane & 15);
        int cb = ks * 64 + ((lane >> 4) << 4);
        pf[mi] = *(const bf16x8*)(PshB + row * 128 + (cb ^ ((row & 7) << 4)));
      }
#pragma unroll
      for (int mi = 0; mi < 2; ++mi) {
#pragma unroll
        for (int ni = 0; ni < 4; ++ni)
          accO[mi][ni] = __builtin_amdgcn_mfma_f32_16x16x32_bf16(pf[mi], vf[ks][ni], accO[mi][ni], 0, 0, 0);
        accO[mi][4] = __builtin_amdgcn_mfma_f32_16x16x32_bf16(pf[mi], vone, accO[mi][4], 0, 0, 0);
      }
    }
    __builtin_amdgcn_s_setprio(0);
#pragma unroll
    for (int ks = 0; ks < 2; ++ks)
#pragma unroll
      for (int ni = 0; ni < 4; ++ni) kfA[ks][ni] = kfB[ks][ni];
  }

  __syncthreads();  // all waves done with P buffers; LB becomes MO partials
  if ((lane >> 4) == 0) {
    MR[w][lane] = mrow[0];
    MR[w][16 + lane] = mrow[1];
  }
  if (w > 0) {
    float* MOw = (float*)LB + (size_t)(w - 1) * 32 * 68;
#pragma unroll
    for (int mi = 0; mi < 2; ++mi) {
#pragma unroll
      for (int r = 0; r < 4; ++r) {
        int rq = mi * 16 + ((lane >> 4) << 2) + r;
#pragma unroll
        for (int ni = 0; ni < 4; ++ni)
          MOw[rq * 68 + ni * 16 + (lane & 15)] = accO[mi][ni][r];
        if ((lane & 15) == 0) MOw[rq * 68 + 64] = accO[mi][4][r];
      }
    }
  }
  __syncthreads();
  if (w == 0) {
    const float* MOp = (const float*)LB;
#pragma unroll
    for (int mi = 0; mi < 2; ++mi) {
#pragma unroll
      for (int r = 0; r < 4; ++r) {
        int rq = mi * 16 + ((lane >> 4) << 2) + r;
        float m0 = MR[0][rq], m1 = MR[1][rq], m2 = MR[2][rq], m3 = MR[3][rq];
        float M = fmaxf(fmaxf(m0, m1), fmaxf(m2, m3));
        float a0 = exp2f(m0 - M), a1 = exp2f(m1 - M);
        float a2 = exp2f(m2 - M), a3 = exp2f(m3 - M);
        float denom = a0 * accO[mi][4][r] + a1 * MOp[(0 * 32 + rq) * 68 + 64] +
                      a2 * MOp[(1 * 32 + rq) * 68 + 64] + a3 * MOp[(2 * 32 + rq) * 68 + 64];
        float inv = 1.0f / denom;
        int t = q0w + rq;
#pragma unroll
        for (int ni = 0; ni < 4; ++ni) {
          int dh = ni * 16 + (lane & 15);
          float o = a0 * accO[mi][ni][r] + a1 * MOp[(0 * 32 + rq) * 68 + dh] +
                    a2 * MOp[(1 * 32 + rq) * 68 + dh] + a3 * MOp[(2 * 32 + rq) * 68 + dh];
          AO[(size_t)t * DD + h * DK + dh] = f2bf(o * inv);
        }
      }
    }
  }
}

// ---------------- output projection + bias (bf16 A, f32 W inline-cvt) -------
// 128x64 tile, 4 waves x (32 x 64), BK=64; grid (16,16) = 1 block/CU.
__global__ __launch_bounds__(256) void gemm_o(
    const unsigned short* __restrict__ A, const float* __restrict__ Wf,
    const float* __restrict__ bias, float* __restrict__ out) {
  __shared__ unsigned short Ash[128 * 64];
  __shared__ unsigned short Bsh[64 * 64];
  const int brow = blockIdx.x * 128;
  const int bcol = blockIdx.y * 64;
  const int tid = threadIdx.x;
  const int lane = tid & 63;
  const int w = tid >> 6;
  const char* Ab = (const char*)A + (size_t)brow * (DD * 2);
  char* AshB = (char*)Ash;
  char* BshB = (char*)Bsh;
  f32x4 acc[2][4];
#pragma unroll
  for (int mi = 0; mi < 2; ++mi)
#pragma unroll
    for (int ni = 0; ni < 4; ++ni)
#pragma unroll
      for (int r = 0; r < 4; ++r) acc[mi][ni][r] = 0.0f;

  for (int k0 = 0; k0 < DD; k0 += 64) {
    __syncthreads();
#pragma unroll
    for (int it = 0; it < 4; ++it) {  // A: bf16 via global_load_lds
      int c = it * 256 + tid;
      int row = c >> 3;
      int xb = (c & 7) << 4;
      int sxb = xb ^ ((row & 7) << 4);
      int ldso = (it * 256 + (tid & 192)) << 4;
      gload16(Ab + (size_t)row * (DD * 2) + k0 * 2 + sxb, AshB + ldso);
    }
    stage_f32<2>(Wf + (size_t)bcol * DD + k0, BshB, tid);  // B: f32 inline-cvt
    __syncthreads();
#pragma unroll
    for (int ks = 0; ks < 2; ++ks) {
      bf16x8 af[2], bfr[4];
      int colb = ks * 64 + ((lane >> 4) << 4);
#pragma unroll
      for (int mi = 0; mi < 2; ++mi) {
        int row = w * 32 + mi * 16 + (lane & 15);
        af[mi] = *(const bf16x8*)(AshB + row * 128 + (colb ^ ((row & 7) << 4)));
      }
#pragma unroll
      for (int ni = 0; ni < 4; ++ni) {
        int row = ni * 16 + (lane & 15);
        bfr[ni] = *(const bf16x8*)(BshB + row * 128 + (colb ^ ((row & 7) << 4)));
      }
#pragma unroll
      for (int mi = 0; mi < 2; ++mi)
#pragma unroll
        for (int ni = 0; ni < 4; ++ni)
          acc[mi][ni] = __builtin_amdgcn_mfma_f32_16x16x32_bf16(af[mi], bfr[ni], acc[mi][ni], 0, 0, 0);
    }
  }
#pragma unroll
  for (int mi = 0; mi < 2; ++mi)
#pragma unroll
    for (int r = 0; r < 4; ++r) {
      int t = brow + w * 32 + mi * 16 + ((lane >> 4) << 2) + r;
#pragma unroll
      for (int ni = 0; ni < 4; ++ni) {
        int o = bcol + ni * 16 + (lane & 15);
        out[(size_t)t * DD + o] = acc[mi][ni][r] + bias[o];
      }
    }
}

// ---------------- launch ----------------
extern "C" void kernel_launch(void* const* d_in, const int* in_sizes, int n_in,
                              void* d_out, int out_size, void* d_ws, size_t ws_size,
                              hipStream_t stream) {
  const float* q  = (const float*)d_in[0];
  const float* k  = (const float*)d_in[1];
  const float* v  = (const float*)d_in[2];
  const int* pos  = (const int*)d_in[3];
  const float* wq = (const float*)d_in[4];
  const float* wk = (const float*)d_in[5];
  const float* wv = (const float*)d_in[6];
  const float* wo = (const float*)d_in[7];
  const float* wob = (const float*)d_in[8];
  float* out = (float*)d_out;
  char* ws = (char*)d_ws;

  const size_t MB = 1u << 20;
  unsigned short* QF = (unsigned short*)(ws + 0 * MB);
  unsigned short* KF = (unsigned short*)(ws + 4 * MB);
  unsigned short* VF = (unsigned short*)(ws + 8 * MB);
  unsigned short* AOb = (unsigned short*)(ws + 12 * MB);
  float* COS = (float*)(ws + 16 * MB);
  float* SIN = (float*)(ws + 16 * MB + 262144);

  hipLaunchKernelGGL(rope_tab, dim3(256), dim3(256), 0, stream, pos, COS, SIN);
  hipLaunchKernelGGL(gemm_qkv, dim3(16, 16, 3), dim3(256), 0, stream,
                     q, k, v, wq, wk, wv, QF, KF, VF, COS, SIN);
  hipLaunchKernelGGL(attn_fa, dim3(1024), dim3(256), 0, stream, QF, KF, VF, AOb);
  hipLaunchKernelGGL(gemm_o, dim3(16, 16), dim3(256), 0, stream, AOb, wo, wob, out);
}

// Round 9
// 78.649 us; speedup vs baseline: 1.2086x; 1.2086x over previous
//
#include <hip/hip_runtime.h>
#include <hip/hip_bf16.h>
#include <stdint.h>

#define TT 2048
#define DD 1024
#define NH 16
#define DK 64

typedef __attribute__((ext_vector_type(8))) short bf16x8;
typedef __attribute__((ext_vector_type(4))) float f32x4;
typedef __attribute__((ext_vector_type(8))) unsigned short u16x8;
typedef __attribute__((ext_vector_type(4))) unsigned short u16x4;

__device__ __forceinline__ unsigned short f2bf(float f) {
  union { float f; unsigned u; } x; x.f = f;
  unsigned r = (x.u + 0x7FFFu + ((x.u >> 16) & 1u)) >> 16;
  return (unsigned short)r;
}

__device__ __forceinline__ void gload16(const void* g, void* l) {
  __builtin_amdgcn_global_load_lds(
      (const __attribute__((address_space(1))) unsigned int*)g,
      (__attribute__((address_space(3))) unsigned int*)l, 16, 0, 0);
}

// ---------------- convert f32 -> bf16 ----------------
__global__ __launch_bounds__(256) void cvt_all(
    const float* __restrict__ q, const float* __restrict__ k, const float* __restrict__ v,
    const float* __restrict__ wq, const float* __restrict__ wk, const float* __restrict__ wv,
    const float* __restrict__ wo,
    unsigned short* __restrict__ oq, unsigned short* __restrict__ ok, unsigned short* __restrict__ ov,
    unsigned short* __restrict__ owq, unsigned short* __restrict__ owk, unsigned short* __restrict__ owv,
    unsigned short* __restrict__ owo) {
  int b = blockIdx.x;
  const float* src; unsigned short* dst; int sb;
  if (b < 1024)      { src = q;  dst = oq;  sb = b; }
  else if (b < 2048) { src = k;  dst = ok;  sb = b - 1024; }
  else if (b < 3072) { src = v;  dst = ov;  sb = b - 2048; }
  else if (b < 3584) { src = wq; dst = owq; sb = b - 3072; }
  else if (b < 4096) { src = wk; dst = owk; sb = b - 3584; }
  else if (b < 4608) { src = wv; dst = owv; sb = b - 4096; }
  else               { src = wo; dst = owo; sb = b - 4608; }
  size_t i0 = (size_t)sb * 2048 + (size_t)threadIdx.x * 8;
  f32x4 a = *(const f32x4*)(src + i0);
  f32x4 c = *(const f32x4*)(src + i0 + 4);
  u16x8 r;
#pragma unroll
  for (int j = 0; j < 4; ++j) { r[j] = f2bf(a[j]); r[j + 4] = f2bf(c[j]); }
  *(u16x8*)(dst + i0) = r;
}

// ---------------- RoPE cos/sin table ----------------
__global__ __launch_bounds__(256) void rope_tab(const int* __restrict__ pos,
                                                float* __restrict__ cosT,
                                                float* __restrict__ sinT) {
  int idx = blockIdx.x * 256 + threadIdx.x;  // 2048*32
  int t = idx >> 5, i = idx & 31;
  float inv = exp2f((float)i * -0.41524101186092028f);  // 10000^(-i/32)
  float ang = (float)pos[t] * inv;
  cosT[idx] = cosf(ang);
  sinT[idx] = sinf(ang);
}

// ---------------- fused QKV projection + RoPE (R7-verified) ----------------
// Outputs in MFMA FRAGMENT-NATIVE layouts (attn loads = base + lane*16):
//  QF[h][qw][mi][ks][lane], KF[h][kt][ks][ni][lane], VF[h][kt][ks][ni][lane]
__global__ __launch_bounds__(256) void gemm_qkv(
    const unsigned short* __restrict__ xq, const unsigned short* __restrict__ xk,
    const unsigned short* __restrict__ xv,
    const unsigned short* __restrict__ wqb, const unsigned short* __restrict__ wkb,
    const unsigned short* __restrict__ wvb,
    unsigned short* __restrict__ QF, unsigned short* __restrict__ KF,
    unsigned short* __restrict__ VF,
    const float* __restrict__ cosT, const float* __restrict__ sinT) {
  __shared__ unsigned short Ash[128 * 64];
  __shared__ unsigned short Bsh[128 * 64];
  const int z = blockIdx.z;
  const unsigned short* A = (z == 0) ? xq : (z == 1) ? xk : xv;
  const unsigned short* W = (z == 0) ? wqb : (z == 1) ? wkb : wvb;
  const int brow = blockIdx.x * 128;
  const int bcol = blockIdx.y * 128;
  const int tid = threadIdx.x;
  const int lane = tid & 63;
  const int w = tid >> 6;
  const int wr = w >> 1, wc = w & 1;
  const char* Ab = (const char*)A + (size_t)brow * (DD * 2);
  const char* Wb = (const char*)W + (size_t)bcol * (DD * 2);
  char* AshB = (char*)Ash;
  char* BshB = (char*)Bsh;
  f32x4 acc[4][4];
#pragma unroll
  for (int mi = 0; mi < 4; ++mi)
#pragma unroll
    for (int ni = 0; ni < 4; ++ni)
#pragma unroll
      for (int r = 0; r < 4; ++r) acc[mi][ni][r] = 0.0f;

  for (int k0 = 0; k0 < DD; k0 += 64) {
    __syncthreads();
#pragma unroll
    for (int it = 0; it < 4; ++it) {
      int c = it * 256 + tid;
      int row = c >> 3;
      int xb = (c & 7) << 4;
      int sxb = xb ^ ((row & 7) << 4);
      int ldso = (it * 256 + (tid & 192)) << 4;
      gload16(Ab + (size_t)row * (DD * 2) + k0 * 2 + sxb, AshB + ldso);
      gload16(Wb + (size_t)row * (DD * 2) + k0 * 2 + sxb, BshB + ldso);
    }
    __syncthreads();
#pragma unroll
    for (int ks = 0; ks < 2; ++ks) {
      bf16x8 af[4], bfr[4];
      int colb = ks * 64 + ((lane >> 4) << 4);
#pragma unroll
      for (int mi = 0; mi < 4; ++mi) {
        int row = wr * 64 + mi * 16 + (lane & 15);
        af[mi] = *(const bf16x8*)(AshB + row * 128 + (colb ^ ((row & 7) << 4)));
      }
#pragma unroll
      for (int ni = 0; ni < 4; ++ni) {
        int row = wc * 64 + ni * 16 + (lane & 15);
        bfr[ni] = *(const bf16x8*)(BshB + row * 128 + (colb ^ ((row & 7) << 4)));
      }
#pragma unroll
      for (int mi = 0; mi < 4; ++mi)
#pragma unroll
        for (int ni = 0; ni < 4; ++ni)
          acc[mi][ni] = __builtin_amdgcn_mfma_f32_16x16x32_bf16(af[mi], bfr[ni], acc[mi][ni], 0, 0, 0);
    }
  }

  const int hcol = bcol + wc * 64;
  const int h = hcol >> 6;
  if (z == 0) {
    // Q + RoPE + scale(1/8 * log2e) -> QF fragment-native
    const float sc = 0.18033688011112042f;
#pragma unroll
    for (int mi = 0; mi < 4; ++mi) {
#pragma unroll
      for (int r = 0; r < 4; ++r) {
        int t = brow + wr * 64 + mi * 16 + ((lane >> 4) << 2) + r;
        int qw_ = t >> 5, mif = (t >> 4) & 1, r16 = t & 15;
        size_t fb = (((size_t)(h * 64 + qw_) * 2 + mif) * 2) * 1024;  // bytes, ks=0
#pragma unroll
        for (int ni = 0; ni < 2; ++ni) {
          int dl = ni * 16 + (lane & 15);  // d in [0,32)
          float cv = cosT[t * 32 + dl];
          float sv = sinT[t * 32 + dl];
          float x1 = acc[mi][ni][r];
          float x2 = acc[mi][ni + 2][r];
          size_t off = fb + (size_t)(r16 + 16 * (dl >> 3)) * 16 + (dl & 7) * 2;
          *(unsigned short*)((char*)QF + off) = f2bf((x1 * cv - x2 * sv) * sc);
          *(unsigned short*)((char*)QF + off + 1024) = f2bf((x2 * cv + x1 * sv) * sc);
        }
      }
    }
  } else if (z == 1) {
    // K + RoPE -> KF fragment-native
#pragma unroll
    for (int mi = 0; mi < 4; ++mi) {
#pragma unroll
      for (int r = 0; r < 4; ++r) {
        int t = brow + wr * 64 + mi * 16 + ((lane >> 4) << 2) + r;
        int kt = t >> 6, nif = (t >> 4) & 3, r16 = t & 15;
        size_t fb = (((size_t)(h * 32 + kt) * 2) * 4 + nif) * 1024;  // bytes, ks=0
#pragma unroll
        for (int ni = 0; ni < 2; ++ni) {
          int dl = ni * 16 + (lane & 15);
          float cv = cosT[t * 32 + dl];
          float sv = sinT[t * 32 + dl];
          float x1 = acc[mi][ni][r];
          float x2 = acc[mi][ni + 2][r];
          size_t off = fb + (size_t)(r16 + 16 * (dl >> 3)) * 16 + (dl & 7) * 2;
          *(unsigned short*)((char*)KF + off) = f2bf(x1 * cv - x2 * sv);
          *(unsigned short*)((char*)KF + off + 4096) = f2bf(x2 * cv + x1 * sv);  // ks=1
        }
      }
    }
  } else {
    // V -> VF fragment-native
#pragma unroll
    for (int mi = 0; mi < 4; ++mi) {
      int t0 = brow + wr * 64 + mi * 16 + ((lane >> 4) << 2);
      int kt = t0 >> 6, ksf = (t0 & 63) >> 5, slot = (t0 & 31) >> 3, j0 = t0 & 7;
#pragma unroll
      for (int ni = 0; ni < 4; ++ni) {
        int dh = ni * 16 + (lane & 15);
        int lanef = (dh & 15) + 16 * slot;
        size_t off = ((((size_t)(h * 32 + kt) * 2 + ksf) * 4 + ni) * 64 + lanef) * 16 + j0 * 2;
        u16x4 pk;
#pragma unroll
        for (int r = 0; r < 4; ++r) pk[r] = f2bf(acc[mi][ni][r]);
        *(u16x4*)((char*)VF + off) = pk;
      }
    }
  }
}

// ---------------- causal flash attention (unchanged from R7/R8) -------------
__global__ __launch_bounds__(256, 2) void attn_fa(
    const unsigned short* __restrict__ QF, const unsigned short* __restrict__ KF,
    const unsigned short* __restrict__ VF, unsigned short* __restrict__ AO) {
  __shared__ char LB[26624];
  __shared__ float MR[4][32];
  const int tid = threadIdx.x;
  const int lane = tid & 63;
  const int w = tid >> 6;
  const int bid = blockIdx.x;
  const int xcd = bid & 7;
  const int idx = bid >> 3;          // 128 jobs per XCD
  const int h = xcd * 2 + (idx & 1); // 2 heads pinned per XCD
  const int qw = 63 - (idx >> 1);    // biggest jobs dispatch first
  const int q0w = qw * 32;
  const int NT = (qw >> 1) + 1;
  char* PshB = LB + w * 4096;
  const char* Kb = (const char*)KF + (size_t)h * 32 * 8192;  // 8KB per k-tile
  const char* Vb = (const char*)VF + (size_t)h * 32 * 8192;

  bf16x8 qf[2][2];
  {
    const char* Qb = (const char*)QF + (size_t)(h * 64 + qw) * 4096;
#pragma unroll
    for (int mi = 0; mi < 2; ++mi)
#pragma unroll
      for (int ks = 0; ks < 2; ++ks)
        qf[mi][ks] = *(const bf16x8*)(Qb + (mi * 2 + ks) * 1024 + lane * 16);
  }

  bf16x8 vone;
#pragma unroll
  for (int j = 0; j < 8; ++j) vone[j] = (short)0x3F80;  // bf16 1.0

  f32x4 accO[2][5];  // [..][4] = row-sum l (ones-column MFMA)
  float mrow[2];
#pragma unroll
  for (int mi = 0; mi < 2; ++mi) {
    mrow[mi] = -1e30f;
#pragma unroll
    for (int ni = 0; ni < 5; ++ni)
#pragma unroll
      for (int r = 0; r < 4; ++r) accO[mi][ni][r] = 0.0f;
  }

  bf16x8 kfA[2][4], kfB[2][4], vf[2][4];
  {
    int kt0 = (w < NT) ? w : 0;
    const char* p = Kb + (size_t)kt0 * 8192 + lane * 16;
#pragma unroll
    for (int ks = 0; ks < 2; ++ks)
#pragma unroll
      for (int ni = 0; ni < 4; ++ni)
        kfA[ks][ni] = *(const bf16x8*)(p + (ks * 4 + ni) * 1024);
  }

  for (int kt = w; kt < NT; kt += 4) {
    {  // V tile: coalesced; issue early, QK+softmax hides latency
      const char* p = Vb + (size_t)kt * 8192 + lane * 16;
#pragma unroll
      for (int ks = 0; ks < 2; ++ks)
#pragma unroll
        for (int ni = 0; ni < 4; ++ni)
          vf[ks][ni] = *(const bf16x8*)(p + (ks * 4 + ni) * 1024);
    }
    f32x4 s[2][4];
#pragma unroll
    for (int mi = 0; mi < 2; ++mi)
#pragma unroll
      for (int ni = 0; ni < 4; ++ni)
#pragma unroll
        for (int r = 0; r < 4; ++r) s[mi][ni][r] = 0.0f;
    // swapped: S^T[k][q] = K-frag (A) x Q-frag (B)
    __builtin_amdgcn_s_setprio(1);
#pragma unroll
    for (int ks = 0; ks < 2; ++ks)
#pragma unroll
      for (int mi = 0; mi < 2; ++mi)
#pragma unroll
        for (int ni = 0; ni < 4; ++ni)
          s[mi][ni] = __builtin_amdgcn_mfma_f32_16x16x32_bf16(kfA[ks][ni], qf[mi][ks], s[mi][ni], 0, 0, 0);
    __builtin_amdgcn_s_setprio(0);
    if (kt + 4 < NT) {  // prefetch own next K tile
      const char* p = Kb + (size_t)(kt + 4) * 8192 + lane * 16;
#pragma unroll
      for (int ks = 0; ks < 2; ++ks)
#pragma unroll
        for (int ni = 0; ni < 4; ++ni)
          kfB[ks][ni] = *(const bf16x8*)(p + (ks * 4 + ni) * 1024);
    }

    if (kt == NT - 1) {  // diagonal tile: causal mask
#pragma unroll
      for (int mi = 0; mi < 2; ++mi) {
        int qq = q0w + mi * 16 + (lane & 15);
#pragma unroll
        for (int ni = 0; ni < 4; ++ni) {
          int kb = kt * 64 + ni * 16 + ((lane >> 4) << 2);
#pragma unroll
          for (int r = 0; r < 4; ++r)
            if (kb + r > qq) s[mi][ni][r] = -1e30f;
        }
      }
    }
    float rmx[2];
#pragma unroll
    for (int mi = 0; mi < 2; ++mi) {
      f32x4 t;
#pragma unroll
      for (int r = 0; r < 4; ++r)
        t[r] = fmaxf(fmaxf(s[mi][0][r], s[mi][1][r]), fmaxf(s[mi][2][r], s[mi][3][r]));
      float mx = fmaxf(fmaxf(t[0], t[1]), fmaxf(t[2], t[3]));
      mx = fmaxf(mx, __shfl_xor(mx, 16, 64));
      mx = fmaxf(mx, __shfl_xor(mx, 32, 64));
      rmx[mi] = mx;
    }
    bool need = (rmx[0] > mrow[0] + 8.0f) || (rmx[1] > mrow[1] + 8.0f);
    if (__any(need)) {
#pragma unroll
      for (int mi = 0; mi < 2; ++mi) {
        float mn = fmaxf(mrow[mi], rmx[mi]);
        float al = exp2f(mrow[mi] - mn);
        mrow[mi] = mn;
        float ar[4];
#pragma unroll
        for (int r = 0; r < 4; ++r) ar[r] = __shfl(al, ((lane >> 4) << 2) + r, 64);
#pragma unroll
        for (int ni = 0; ni < 5; ++ni)
#pragma unroll
          for (int r = 0; r < 4; ++r) accO[mi][ni][r] *= ar[r];
      }
    }
#pragma unroll
    for (int mi = 0; mi < 2; ++mi) {
      int row = mi * 16 + (lane & 15);
      int rbase = row * 128;
      int sw = (row & 7) << 4;
#pragma unroll
      for (int ni = 0; ni < 4; ++ni) {
        unsigned u0 = __float_as_uint(exp2f(s[mi][ni][0] - mrow[mi]));
        unsigned u1 = __float_as_uint(exp2f(s[mi][ni][1] - mrow[mi]));
        unsigned u2 = __float_as_uint(exp2f(s[mi][ni][2] - mrow[mi]));
        unsigned u3 = __float_as_uint(exp2f(s[mi][ni][3] - mrow[mi]));
        uint2 pk;
        pk.x = (u0 >> 16) | (u1 & 0xFFFF0000u);
        pk.y = (u2 >> 16) | (u3 & 0xFFFF0000u);
        int cb = ni * 32 + ((lane >> 4) << 3);
        *(uint2*)(PshB + rbase + (cb ^ sw)) = pk;
      }
    }
    asm volatile("" ::: "memory");
    __builtin_amdgcn_s_setprio(1);
#pragma unroll
    for (int ks = 0; ks < 2; ++ks) {
      bf16x8 pf[2];
#pragma unroll
      for (int mi = 0; mi < 2; ++mi) {
        int row = mi * 16 + (lane & 15);
        int cb = ks * 64 + ((lane >> 4) << 4);
        pf[mi] = *(const bf16x8*)(PshB + row * 128 + (cb ^ ((row & 7) << 4)));
      }
#pragma unroll
      for (int mi = 0; mi < 2; ++mi) {
#pragma unroll
        for (int ni = 0; ni < 4; ++ni)
          accO[mi][ni] = __builtin_amdgcn_mfma_f32_16x16x32_bf16(pf[mi], vf[ks][ni], accO[mi][ni], 0, 0, 0);
        accO[mi][4] = __builtin_amdgcn_mfma_f32_16x16x32_bf16(pf[mi], vone, accO[mi][4], 0, 0, 0);
      }
    }
    __builtin_amdgcn_s_setprio(0);
#pragma unroll
    for (int ks = 0; ks < 2; ++ks)
#pragma unroll
      for (int ni = 0; ni < 4; ++ni) kfA[ks][ni] = kfB[ks][ni];
  }

  __syncthreads();  // all waves done with P buffers; LB becomes MO partials
  if ((lane >> 4) == 0) {
    MR[w][lane] = mrow[0];
    MR[w][16 + lane] = mrow[1];
  }
  if (w > 0) {
    float* MOw = (float*)LB + (size_t)(w - 1) * 32 * 68;
#pragma unroll
    for (int mi = 0; mi < 2; ++mi) {
#pragma unroll
      for (int r = 0; r < 4; ++r) {
        int rq = mi * 16 + ((lane >> 4) << 2) + r;
#pragma unroll
        for (int ni = 0; ni < 4; ++ni)
          MOw[rq * 68 + ni * 16 + (lane & 15)] = accO[mi][ni][r];
        if ((lane & 15) == 0) MOw[rq * 68 + 64] = accO[mi][4][r];
      }
    }
  }
  __syncthreads();
  if (w == 0) {
    const float* MOp = (const float*)LB;
#pragma unroll
    for (int mi = 0; mi < 2; ++mi) {
#pragma unroll
      for (int r = 0; r < 4; ++r) {
        int rq = mi * 16 + ((lane >> 4) << 2) + r;
        float m0 = MR[0][rq], m1 = MR[1][rq], m2 = MR[2][rq], m3 = MR[3][rq];
        float M = fmaxf(fmaxf(m0, m1), fmaxf(m2, m3));
        float a0 = exp2f(m0 - M), a1 = exp2f(m1 - M);
        float a2 = exp2f(m2 - M), a3 = exp2f(m3 - M);
        float denom = a0 * accO[mi][4][r] + a1 * MOp[(0 * 32 + rq) * 68 + 64] +
                      a2 * MOp[(1 * 32 + rq) * 68 + 64] + a3 * MOp[(2 * 32 + rq) * 68 + 64];
        float inv = 1.0f / denom;
        int t = q0w + rq;
#pragma unroll
        for (int ni = 0; ni < 4; ++ni) {
          int dh = ni * 16 + (lane & 15);
          float o = a0 * accO[mi][ni][r] + a1 * MOp[(0 * 32 + rq) * 68 + dh] +
                    a2 * MOp[(1 * 32 + rq) * 68 + dh] + a3 * MOp[(2 * 32 + rq) * 68 + dh];
          AO[(size_t)t * DD + h * DK + dh] = f2bf(o * inv);
        }
      }
    }
  }
}

// ---------------- output projection + bias (f32 out) ----------------
// 128x64 tile, 4 waves x (32 x 64), BK=64; grid (16,16) = 1 block/CU.
__global__ __launch_bounds__(256) void gemm_o(
    const unsigned short* __restrict__ A, const unsigned short* __restrict__ W,
    const float* __restrict__ bias, float* __restrict__ out) {
  __shared__ unsigned short Ash[128 * 64];
  __shared__ unsigned short Bsh[64 * 64];
  const int brow = blockIdx.x * 128;
  const int bcol = blockIdx.y * 64;
  const int tid = threadIdx.x;
  const int lane = tid & 63;
  const int w = tid >> 6;
  const char* Ab = (const char*)A + (size_t)brow * (DD * 2);
  const char* Wb = (const char*)W + (size_t)bcol * (DD * 2);
  char* AshB = (char*)Ash;
  char* BshB = (char*)Bsh;
  f32x4 acc[2][4];
#pragma unroll
  for (int mi = 0; mi < 2; ++mi)
#pragma unroll
    for (int ni = 0; ni < 4; ++ni)
#pragma unroll
      for (int r = 0; r < 4; ++r) acc[mi][ni][r] = 0.0f;

  for (int k0 = 0; k0 < DD; k0 += 64) {
    __syncthreads();
#pragma unroll
    for (int it = 0; it < 4; ++it) {  // A: 128x64 bf16 = 16KB
      int c = it * 256 + tid;
      int row = c >> 3;
      int xb = (c & 7) << 4;
      int sxb = xb ^ ((row & 7) << 4);
      int ldso = (it * 256 + (tid & 192)) << 4;
      gload16(Ab + (size_t)row * (DD * 2) + k0 * 2 + sxb, AshB + ldso);
    }
#pragma unroll
    for (int it = 0; it < 2; ++it) {  // W: 64x64 bf16 = 8KB
      int c = it * 256 + tid;
      int row = c >> 3;
      int xb = (c & 7) << 4;
      int sxb = xb ^ ((row & 7) << 4);
      int ldso = (it * 256 + (tid & 192)) << 4;
      gload16(Wb + (size_t)row * (DD * 2) + k0 * 2 + sxb, BshB + ldso);
    }
    __syncthreads();
#pragma unroll
    for (int ks = 0; ks < 2; ++ks) {
      bf16x8 af[2], bfr[4];
      int colb = ks * 64 + ((lane >> 4) << 4);
#pragma unroll
      for (int mi = 0; mi < 2; ++mi) {
        int row = w * 32 + mi * 16 + (lane & 15);
        af[mi] = *(const bf16x8*)(AshB + row * 128 + (colb ^ ((row & 7) << 4)));
      }
#pragma unroll
      for (int ni = 0; ni < 4; ++ni) {
        int row = ni * 16 + (lane & 15);
        bfr[ni] = *(const bf16x8*)(BshB + row * 128 + (colb ^ ((row & 7) << 4)));
      }
#pragma unroll
      for (int mi = 0; mi < 2; ++mi)
#pragma unroll
        for (int ni = 0; ni < 4; ++ni)
          acc[mi][ni] = __builtin_amdgcn_mfma_f32_16x16x32_bf16(af[mi], bfr[ni], acc[mi][ni], 0, 0, 0);
    }
  }
#pragma unroll
  for (int mi = 0; mi < 2; ++mi)
#pragma unroll
    for (int r = 0; r < 4; ++r) {
      int t = brow + w * 32 + mi * 16 + ((lane >> 4) << 2) + r;
#pragma unroll
      for (int ni = 0; ni < 4; ++ni) {
        int o = bcol + ni * 16 + (lane & 15);
        out[(size_t)t * DD + o] = acc[mi][ni][r] + bias[o];
      }
    }
}

// ---------------- launch ----------------
extern "C" void kernel_launch(void* const* d_in, const int* in_sizes, int n_in,
                              void* d_out, int out_size, void* d_ws, size_t ws_size,
                              hipStream_t stream) {
  const float* q  = (const float*)d_in[0];
  const float* k  = (const float*)d_in[1];
  const float* v  = (const float*)d_in[2];
  const int* pos  = (const int*)d_in[3];
  const float* wq = (const float*)d_in[4];
  const float* wk = (const float*)d_in[5];
  const float* wv = (const float*)d_in[6];
  const float* wo = (const float*)d_in[7];
  const float* wob = (const float*)d_in[8];
  float* out = (float*)d_out;
  char* ws = (char*)d_ws;

  const size_t MB = 1u << 20;
  unsigned short* XQ = (unsigned short*)(ws + 0 * MB);
  unsigned short* XK = (unsigned short*)(ws + 4 * MB);
  unsigned short* XV = (unsigned short*)(ws + 8 * MB);
  unsigned short* WQ = (unsigned short*)(ws + 12 * MB);
  unsigned short* WK = (unsigned short*)(ws + 14 * MB);
  unsigned short* WV = (unsigned short*)(ws + 16 * MB);
  unsigned short* WO = (unsigned short*)(ws + 18 * MB);
  unsigned short* QF = (unsigned short*)(ws + 20 * MB);
  unsigned short* KF = (unsigned short*)(ws + 24 * MB);
  unsigned short* VF = (unsigned short*)(ws + 28 * MB);
  unsigned short* AOb = (unsigned short*)(ws + 32 * MB);
  float* COS = (float*)(ws + 36 * MB);
  float* SIN = (float*)(ws + 36 * MB + 262144);

  hipLaunchKernelGGL(cvt_all, dim3(5120), dim3(256), 0, stream,
                     q, k, v, wq, wk, wv, wo, XQ, XK, XV, WQ, WK, WV, WO);
  hipLaunchKernelGGL(rope_tab, dim3(256), dim3(256), 0, stream, pos, COS, SIN);
  hipLaunchKernelGGL(gemm_qkv, dim3(16, 8, 3), dim3(256), 0, stream,
                     XQ, XK, XV, WQ, WK, WV, QF, KF, VF, COS, SIN);
  hipLaunchKernelGGL(attn_fa, dim3(1024), dim3(256), 0, stream, QF, KF, VF, AOb);
  hipLaunchKernelGGL(gemm_o, dim3(16, 16), dim3(256), 0, stream, AOb, WO, wob, out);
}

// Round 10
// 71.841 us; speedup vs baseline: 1.3232x; 1.0948x over previous
//
#include <hip/hip_runtime.h>
#include <hip/hip_bf16.h>
#include <stdint.h>

#define TT 2048
#define DD 1024
#define NH 16
#define DK 64

typedef __attribute__((ext_vector_type(8))) short bf16x8;
typedef __attribute__((ext_vector_type(4))) float f32x4;
typedef __attribute__((ext_vector_type(8))) unsigned short u16x8;
typedef __attribute__((ext_vector_type(4))) unsigned short u16x4;

__device__ __forceinline__ unsigned short f2bf(float f) {
  union { float f; unsigned u; } x; x.f = f;
  unsigned r = (x.u + 0x7FFFu + ((x.u >> 16) & 1u)) >> 16;
  return (unsigned short)r;
}

__device__ __forceinline__ void gload16(const void* g, void* l) {
  __builtin_amdgcn_global_load_lds(
      (const __attribute__((address_space(1))) unsigned int*)g,
      (__attribute__((address_space(3))) unsigned int*)l, 16, 0, 0);
}

// ---------------- convert f32 -> bf16  (+ fused RoPE table) ----------------
__global__ __launch_bounds__(256) void cvt_all(
    const float* __restrict__ q, const float* __restrict__ k, const float* __restrict__ v,
    const float* __restrict__ wq, const float* __restrict__ wk, const float* __restrict__ wv,
    const float* __restrict__ wo,
    unsigned short* __restrict__ oq, unsigned short* __restrict__ ok, unsigned short* __restrict__ ov,
    unsigned short* __restrict__ owq, unsigned short* __restrict__ owk, unsigned short* __restrict__ owv,
    unsigned short* __restrict__ owo,
    const int* __restrict__ pos, float* __restrict__ cosT, float* __restrict__ sinT) {
  int b = blockIdx.x;
  if (b >= 5120) {  // RoPE cos/sin table: 2048*32 entries over 256 blocks
    int idx = (b - 5120) * 256 + threadIdx.x;
    int t = idx >> 5, i = idx & 31;
    float inv = exp2f((float)i * -0.41524101186092028f);  // 10000^(-i/32)
    float ang = (float)pos[t] * inv;
    cosT[idx] = cosf(ang);
    sinT[idx] = sinf(ang);
    return;
  }
  const float* src; unsigned short* dst; int sb;
  if (b < 1024)      { src = q;  dst = oq;  sb = b; }
  else if (b < 2048) { src = k;  dst = ok;  sb = b - 1024; }
  else if (b < 3072) { src = v;  dst = ov;  sb = b - 2048; }
  else if (b < 3584) { src = wq; dst = owq; sb = b - 3072; }
  else if (b < 4096) { src = wk; dst = owk; sb = b - 3584; }
  else if (b < 4608) { src = wv; dst = owv; sb = b - 4096; }
  else               { src = wo; dst = owo; sb = b - 4608; }
  size_t i0 = (size_t)sb * 2048 + (size_t)threadIdx.x * 8;
  f32x4 a = *(const f32x4*)(src + i0);
  f32x4 c = *(const f32x4*)(src + i0 + 4);
  u16x8 r;
#pragma unroll
  for (int j = 0; j < 4; ++j) { r[j] = f2bf(a[j]); r[j + 4] = f2bf(c[j]); }
  *(u16x8*)(dst + i0) = r;
}

// ---------------- fused QKV projection + RoPE ----------------
// BM=64 x BN=128, grid (32,8,3) = 768 blocks = 3 blocks/CU (vs 1.5 at BM=128).
// 4 waves: wr=w>>1 (32-row half), wc=w&1 (64-col half); acc[2][4].
// Outputs in MFMA FRAGMENT-NATIVE layouts (attn loads = base + lane*16):
//  QF[h][qw][mi][ks][lane], KF[h][kt][ks][ni][lane], VF[h][kt][ks][ni][lane]
__global__ __launch_bounds__(256) void gemm_qkv(
    const unsigned short* __restrict__ xq, const unsigned short* __restrict__ xk,
    const unsigned short* __restrict__ xv,
    const unsigned short* __restrict__ wqb, const unsigned short* __restrict__ wkb,
    const unsigned short* __restrict__ wvb,
    unsigned short* __restrict__ QF, unsigned short* __restrict__ KF,
    unsigned short* __restrict__ VF,
    const float* __restrict__ cosT, const float* __restrict__ sinT) {
  __shared__ unsigned short Ash[64 * 64];
  __shared__ unsigned short Bsh[128 * 64];
  const int z = blockIdx.z;
  const unsigned short* A = (z == 0) ? xq : (z == 1) ? xk : xv;
  const unsigned short* W = (z == 0) ? wqb : (z == 1) ? wkb : wvb;
  const int brow = blockIdx.x * 64;
  const int bcol = blockIdx.y * 128;
  const int tid = threadIdx.x;
  const int lane = tid & 63;
  const int w = tid >> 6;
  const int wr = w >> 1, wc = w & 1;
  const char* Ab = (const char*)A + (size_t)brow * (DD * 2);
  const char* Wb = (const char*)W + (size_t)bcol * (DD * 2);
  char* AshB = (char*)Ash;
  char* BshB = (char*)Bsh;
  f32x4 acc[2][4];
#pragma unroll
  for (int mi = 0; mi < 2; ++mi)
#pragma unroll
    for (int ni = 0; ni < 4; ++ni)
#pragma unroll
      for (int r = 0; r < 4; ++r) acc[mi][ni][r] = 0.0f;

  for (int k0 = 0; k0 < DD; k0 += 64) {
    __syncthreads();
#pragma unroll
    for (int it = 0; it < 2; ++it) {  // A: 64x64 bf16 = 8KB
      int c = it * 256 + tid;
      int row = c >> 3;
      int xb = (c & 7) << 4;
      int sxb = xb ^ ((row & 7) << 4);
      int ldso = (it * 256 + (tid & 192)) << 4;
      gload16(Ab + (size_t)row * (DD * 2) + k0 * 2 + sxb, AshB + ldso);
    }
#pragma unroll
    for (int it = 0; it < 4; ++it) {  // B: 128x64 bf16 = 16KB
      int c = it * 256 + tid;
      int row = c >> 3;
      int xb = (c & 7) << 4;
      int sxb = xb ^ ((row & 7) << 4);
      int ldso = (it * 256 + (tid & 192)) << 4;
      gload16(Wb + (size_t)row * (DD * 2) + k0 * 2 + sxb, BshB + ldso);
    }
    __syncthreads();
#pragma unroll
    for (int ks = 0; ks < 2; ++ks) {
      bf16x8 af[2], bfr[4];
      int colb = ks * 64 + ((lane >> 4) << 4);
#pragma unroll
      for (int mi = 0; mi < 2; ++mi) {
        int row = wr * 32 + mi * 16 + (lane & 15);
        af[mi] = *(const bf16x8*)(AshB + row * 128 + (colb ^ ((row & 7) << 4)));
      }
#pragma unroll
      for (int ni = 0; ni < 4; ++ni) {
        int row = wc * 64 + ni * 16 + (lane & 15);
        bfr[ni] = *(const bf16x8*)(BshB + row * 128 + (colb ^ ((row & 7) << 4)));
      }
#pragma unroll
      for (int mi = 0; mi < 2; ++mi)
#pragma unroll
        for (int ni = 0; ni < 4; ++ni)
          acc[mi][ni] = __builtin_amdgcn_mfma_f32_16x16x32_bf16(af[mi], bfr[ni], acc[mi][ni], 0, 0, 0);
    }
  }

  const int hcol = bcol + wc * 64;
  const int h = hcol >> 6;
  if (z == 0) {
    // Q + RoPE + scale(1/8 * log2e) -> QF fragment-native
    const float sc = 0.18033688011112042f;
#pragma unroll
    for (int mi = 0; mi < 2; ++mi) {
#pragma unroll
      for (int r = 0; r < 4; ++r) {
        int t = brow + wr * 32 + mi * 16 + ((lane >> 4) << 2) + r;
        int qw_ = t >> 5, mif = (t >> 4) & 1, r16 = t & 15;
        size_t fb = (((size_t)(h * 64 + qw_) * 2 + mif) * 2) * 1024;  // bytes, ks=0
#pragma unroll
        for (int ni = 0; ni < 2; ++ni) {
          int dl = ni * 16 + (lane & 15);  // d in [0,32)
          float cv = cosT[t * 32 + dl];
          float sv = sinT[t * 32 + dl];
          float x1 = acc[mi][ni][r];
          float x2 = acc[mi][ni + 2][r];
          size_t off = fb + (size_t)(r16 + 16 * (dl >> 3)) * 16 + (dl & 7) * 2;
          *(unsigned short*)((char*)QF + off) = f2bf((x1 * cv - x2 * sv) * sc);
          *(unsigned short*)((char*)QF + off + 1024) = f2bf((x2 * cv + x1 * sv) * sc);
        }
      }
    }
  } else if (z == 1) {
    // K + RoPE -> KF fragment-native
#pragma unroll
    for (int mi = 0; mi < 2; ++mi) {
#pragma unroll
      for (int r = 0; r < 4; ++r) {
        int t = brow + wr * 32 + mi * 16 + ((lane >> 4) << 2) + r;
        int kt = t >> 6, nif = (t >> 4) & 3, r16 = t & 15;
        size_t fb = (((size_t)(h * 32 + kt) * 2) * 4 + nif) * 1024;  // bytes, ks=0
#pragma unroll
        for (int ni = 0; ni < 2; ++ni) {
          int dl = ni * 16 + (lane & 15);
          float cv = cosT[t * 32 + dl];
          float sv = sinT[t * 32 + dl];
          float x1 = acc[mi][ni][r];
          float x2 = acc[mi][ni + 2][r];
          size_t off = fb + (size_t)(r16 + 16 * (dl >> 3)) * 16 + (dl & 7) * 2;
          *(unsigned short*)((char*)KF + off) = f2bf(x1 * cv - x2 * sv);
          *(unsigned short*)((char*)KF + off + 4096) = f2bf(x2 * cv + x1 * sv);  // ks=1
        }
      }
    }
  } else {
    // V -> VF fragment-native
#pragma unroll
    for (int mi = 0; mi < 2; ++mi) {
      int t0 = brow + wr * 32 + mi * 16 + ((lane >> 4) << 2);
      int kt = t0 >> 6, ksf = (t0 & 63) >> 5, slot = (t0 & 31) >> 3, j0 = t0 & 7;
#pragma unroll
      for (int ni = 0; ni < 4; ++ni) {
        int dh = ni * 16 + (lane & 15);
        int lanef = (dh & 15) + 16 * slot;
        size_t off = ((((size_t)(h * 32 + kt) * 2 + ksf) * 4 + ni) * 64 + lanef) * 16 + j0 * 2;
        u16x4 pk;
#pragma unroll
        for (int r = 0; r < 4; ++r) pk[r] = f2bf(acc[mi][ni][r]);
        *(u16x4*)((char*)VF + off) = pk;
      }
    }
  }
}

// ---------------- causal flash attention (unchanged, R7-verified) -----------
__global__ __launch_bounds__(256, 2) void attn_fa(
    const unsigned short* __restrict__ QF, const unsigned short* __restrict__ KF,
    const unsigned short* __restrict__ VF, unsigned short* __restrict__ AO) {
  __shared__ char LB[26624];
  __shared__ float MR[4][32];
  const int tid = threadIdx.x;
  const int lane = tid & 63;
  const int w = tid >> 6;
  const int bid = blockIdx.x;
  const int xcd = bid & 7;
  const int idx = bid >> 3;          // 128 jobs per XCD
  const int h = xcd * 2 + (idx & 1); // 2 heads pinned per XCD
  const int qw = 63 - (idx >> 1);    // biggest jobs dispatch first
  const int q0w = qw * 32;
  const int NT = (qw >> 1) + 1;
  char* PshB = LB + w * 4096;
  const char* Kb = (const char*)KF + (size_t)h * 32 * 8192;  // 8KB per k-tile
  const char* Vb = (const char*)VF + (size_t)h * 32 * 8192;

  bf16x8 qf[2][2];
  {
    const char* Qb = (const char*)QF + (size_t)(h * 64 + qw) * 4096;
#pragma unroll
    for (int mi = 0; mi < 2; ++mi)
#pragma unroll
      for (int ks = 0; ks < 2; ++ks)
        qf[mi][ks] = *(const bf16x8*)(Qb + (mi * 2 + ks) * 1024 + lane * 16);
  }

  bf16x8 vone;
#pragma unroll
  for (int j = 0; j < 8; ++j) vone[j] = (short)0x3F80;  // bf16 1.0

  f32x4 accO[2][5];  // [..][4] = row-sum l (ones-column MFMA)
  float mrow[2];
#pragma unroll
  for (int mi = 0; mi < 2; ++mi) {
    mrow[mi] = -1e30f;
#pragma unroll
    for (int ni = 0; ni < 5; ++ni)
#pragma unroll
      for (int r = 0; r < 4; ++r) accO[mi][ni][r] = 0.0f;
  }

  bf16x8 kfA[2][4], kfB[2][4], vf[2][4];
  {
    int kt0 = (w < NT) ? w : 0;
    const char* p = Kb + (size_t)kt0 * 8192 + lane * 16;
#pragma unroll
    for (int ks = 0; ks < 2; ++ks)
#pragma unroll
      for (int ni = 0; ni < 4; ++ni)
        kfA[ks][ni] = *(const bf16x8*)(p + (ks * 4 + ni) * 1024);
  }

  for (int kt = w; kt < NT; kt += 4) {
    {  // V tile: coalesced; issue early, QK+softmax hides latency
      const char* p = Vb + (size_t)kt * 8192 + lane * 16;
#pragma unroll
      for (int ks = 0; ks < 2; ++ks)
#pragma unroll
        for (int ni = 0; ni < 4; ++ni)
          vf[ks][ni] = *(const bf16x8*)(p + (ks * 4 + ni) * 1024);
    }
    f32x4 s[2][4];
#pragma unroll
    for (int mi = 0; mi < 2; ++mi)
#pragma unroll
      for (int ni = 0; ni < 4; ++ni)
#pragma unroll
        for (int r = 0; r < 4; ++r) s[mi][ni][r] = 0.0f;
    // swapped: S^T[k][q] = K-frag (A) x Q-frag (B)
    __builtin_amdgcn_s_setprio(1);
#pragma unroll
    for (int ks = 0; ks < 2; ++ks)
#pragma unroll
      for (int mi = 0; mi < 2; ++mi)
#pragma unroll
        for (int ni = 0; ni < 4; ++ni)
          s[mi][ni] = __builtin_amdgcn_mfma_f32_16x16x32_bf16(kfA[ks][ni], qf[mi][ks], s[mi][ni], 0, 0, 0);
    __builtin_amdgcn_s_setprio(0);
    if (kt + 4 < NT) {  // prefetch own next K tile
      const char* p = Kb + (size_t)(kt + 4) * 8192 + lane * 16;
#pragma unroll
      for (int ks = 0; ks < 2; ++ks)
#pragma unroll
        for (int ni = 0; ni < 4; ++ni)
          kfB[ks][ni] = *(const bf16x8*)(p + (ks * 4 + ni) * 1024);
    }

    if (kt == NT - 1) {  // diagonal tile: causal mask
#pragma unroll
      for (int mi = 0; mi < 2; ++mi) {
        int qq = q0w + mi * 16 + (lane & 15);
#pragma unroll
        for (int ni = 0; ni < 4; ++ni) {
          int kb = kt * 64 + ni * 16 + ((lane >> 4) << 2);
#pragma unroll
          for (int r = 0; r < 4; ++r)
            if (kb + r > qq) s[mi][ni][r] = -1e30f;
        }
      }
    }
    float rmx[2];
#pragma unroll
    for (int mi = 0; mi < 2; ++mi) {
      f32x4 t;
#pragma unroll
      for (int r = 0; r < 4; ++r)
        t[r] = fmaxf(fmaxf(s[mi][0][r], s[mi][1][r]), fmaxf(s[mi][2][r], s[mi][3][r]));
      float mx = fmaxf(fmaxf(t[0], t[1]), fmaxf(t[2], t[3]));
      mx = fmaxf(mx, __shfl_xor(mx, 16, 64));
      mx = fmaxf(mx, __shfl_xor(mx, 32, 64));
      rmx[mi] = mx;
    }
    bool need = (rmx[0] > mrow[0] + 8.0f) || (rmx[1] > mrow[1] + 8.0f);
    if (__any(need)) {
#pragma unroll
      for (int mi = 0; mi < 2; ++mi) {
        float mn = fmaxf(mrow[mi], rmx[mi]);
        float al = exp2f(mrow[mi] - mn);
        mrow[mi] = mn;
        float ar[4];
#pragma unroll
        for (int r = 0; r < 4; ++r) ar[r] = __shfl(al, ((lane >> 4) << 2) + r, 64);
#pragma unroll
        for (int ni = 0; ni < 5; ++ni)
#pragma unroll
          for (int r = 0; r < 4; ++r) accO[mi][ni][r] *= ar[r];
      }
    }
#pragma unroll
    for (int mi = 0; mi < 2; ++mi) {
      int row = mi * 16 + (lane & 15);
      int rbase = row * 128;
      int sw = (row & 7) << 4;
#pragma unroll
      for (int ni = 0; ni < 4; ++ni) {
        unsigned u0 = __float_as_uint(exp2f(s[mi][ni][0] - mrow[mi]));
        unsigned u1 = __float_as_uint(exp2f(s[mi][ni][1] - mrow[mi]));
        unsigned u2 = __float_as_uint(exp2f(s[mi][ni][2] - mrow[mi]));
        unsigned u3 = __float_as_uint(exp2f(s[mi][ni][3] - mrow[mi]));
        uint2 pk;
        pk.x = (u0 >> 16) | (u1 & 0xFFFF0000u);
        pk.y = (u2 >> 16) | (u3 & 0xFFFF0000u);
        int cb = ni * 32 + ((lane >> 4) << 3);
        *(uint2*)(PshB + rbase + (cb ^ sw)) = pk;
      }
    }
    asm volatile("" ::: "memory");
    __builtin_amdgcn_s_setprio(1);
#pragma unroll
    for (int ks = 0; ks < 2; ++ks) {
      bf16x8 pf[2];
#pragma unroll
      for (int mi = 0; mi < 2; ++mi) {
        int row = mi * 16 + (lane & 15);
        int cb = ks * 64 + ((lane >> 4) << 4);
        pf[mi] = *(const bf16x8*)(PshB + row * 128 + (cb ^ ((row & 7) << 4)));
      }
#pragma unroll
      for (int mi = 0; mi < 2; ++mi) {
#pragma unroll
        for (int ni = 0; ni < 4; ++ni)
          accO[mi][ni] = __builtin_amdgcn_mfma_f32_16x16x32_bf16(pf[mi], vf[ks][ni], accO[mi][ni], 0, 0, 0);
        accO[mi][4] = __builtin_amdgcn_mfma_f32_16x16x32_bf16(pf[mi], vone, accO[mi][4], 0, 0, 0);
      }
    }
    __builtin_amdgcn_s_setprio(0);
#pragma unroll
    for (int ks = 0; ks < 2; ++ks)
#pragma unroll
      for (int ni = 0; ni < 4; ++ni) kfA[ks][ni] = kfB[ks][ni];
  }

  __syncthreads();  // all waves done with P buffers; LB becomes MO partials
  if ((lane >> 4) == 0) {
    MR[w][lane] = mrow[0];
    MR[w][16 + lane] = mrow[1];
  }
  if (w > 0) {
    float* MOw = (float*)LB + (size_t)(w - 1) * 32 * 68;
#pragma unroll
    for (int mi = 0; mi < 2; ++mi) {
#pragma unroll
      for (int r = 0; r < 4; ++r) {
        int rq = mi * 16 + ((lane >> 4) << 2) + r;
#pragma unroll
        for (int ni = 0; ni < 4; ++ni)
          MOw[rq * 68 + ni * 16 + (lane & 15)] = accO[mi][ni][r];
        if ((lane & 15) == 0) MOw[rq * 68 + 64] = accO[mi][4][r];
      }
    }
  }
  __syncthreads();
  if (w == 0) {
    const float* MOp = (const float*)LB;
#pragma unroll
    for (int mi = 0; mi < 2; ++mi) {
#pragma unroll
      for (int r = 0; r < 4; ++r) {
        int rq = mi * 16 + ((lane >> 4) << 2) + r;
        float m0 = MR[0][rq], m1 = MR[1][rq], m2 = MR[2][rq], m3 = MR[3][rq];
        float M = fmaxf(fmaxf(m0, m1), fmaxf(m2, m3));
        float a0 = exp2f(m0 - M), a1 = exp2f(m1 - M);
        float a2 = exp2f(m2 - M), a3 = exp2f(m3 - M);
        float denom = a0 * accO[mi][4][r] + a1 * MOp[(0 * 32 + rq) * 68 + 64] +
                      a2 * MOp[(1 * 32 + rq) * 68 + 64] + a3 * MOp[(2 * 32 + rq) * 68 + 64];
        float inv = 1.0f / denom;
        int t = q0w + rq;
#pragma unroll
        for (int ni = 0; ni < 4; ++ni) {
          int dh = ni * 16 + (lane & 15);
          float o = a0 * accO[mi][ni][r] + a1 * MOp[(0 * 32 + rq) * 68 + dh] +
                    a2 * MOp[(1 * 32 + rq) * 68 + dh] + a3 * MOp[(2 * 32 + rq) * 68 + dh];
          AO[(size_t)t * DD + h * DK + dh] = f2bf(o * inv);
        }
      }
    }
  }
}

// ---------------- output projection + bias (f32 out, unchanged) -------------
// 128x64 tile, 4 waves x (32 x 64), BK=64; grid (16,16) = 1 block/CU.
__global__ __launch_bounds__(256) void gemm_o(
    const unsigned short* __restrict__ A, const unsigned short* __restrict__ W,
    const float* __restrict__ bias, float* __restrict__ out) {
  __shared__ unsigned short Ash[128 * 64];
  __shared__ unsigned short Bsh[64 * 64];
  const int brow = blockIdx.x * 128;
  const int bcol = blockIdx.y * 64;
  const int tid = threadIdx.x;
  const int lane = tid & 63;
  const int w = tid >> 6;
  const char* Ab = (const char*)A + (size_t)brow * (DD * 2);
  const char* Wb = (const char*)W + (size_t)bcol * (DD * 2);
  char* AshB = (char*)Ash;
  char* BshB = (char*)Bsh;
  f32x4 acc[2][4];
#pragma unroll
  for (int mi = 0; mi < 2; ++mi)
#pragma unroll
    for (int ni = 0; ni < 4; ++ni)
#pragma unroll
      for (int r = 0; r < 4; ++r) acc[mi][ni][r] = 0.0f;

  for (int k0 = 0; k0 < DD; k0 += 64) {
    __syncthreads();
#pragma unroll
    for (int it = 0; it < 4; ++it) {  // A: 128x64 bf16 = 16KB
      int c = it * 256 + tid;
      int row = c >> 3;
      int xb = (c & 7) << 4;
      int sxb = xb ^ ((row & 7) << 4);
      int ldso = (it * 256 + (tid & 192)) << 4;
      gload16(Ab + (size_t)row * (DD * 2) + k0 * 2 + sxb, AshB + ldso);
    }
#pragma unroll
    for (int it = 0; it < 2; ++it) {  // W: 64x64 bf16 = 8KB
      int c = it * 256 + tid;
      int row = c >> 3;
      int xb = (c & 7) << 4;
      int sxb = xb ^ ((row & 7) << 4);
      int ldso = (it * 256 + (tid & 192)) << 4;
      gload16(Wb + (size_t)row * (DD * 2) + k0 * 2 + sxb, BshB + ldso);
    }
    __syncthreads();
#pragma unroll
    for (int ks = 0; ks < 2; ++ks) {
      bf16x8 af[2], bfr[4];
      int colb = ks * 64 + ((lane >> 4) << 4);
#pragma unroll
      for (int mi = 0; mi < 2; ++mi) {
        int row = w * 32 + mi * 16 + (lane & 15);
        af[mi] = *(const bf16x8*)(AshB + row * 128 + (colb ^ ((row & 7) << 4)));
      }
#pragma unroll
      for (int ni = 0; ni < 4; ++ni) {
        int row = ni * 16 + (lane & 15);
        bfr[ni] = *(const bf16x8*)(BshB + row * 128 + (colb ^ ((row & 7) << 4)));
      }
#pragma unroll
      for (int mi = 0; mi < 2; ++mi)
#pragma unroll
        for (int ni = 0; ni < 4; ++ni)
          acc[mi][ni] = __builtin_amdgcn_mfma_f32_16x16x32_bf16(af[mi], bfr[ni], acc[mi][ni], 0, 0, 0);
    }
  }
#pragma unroll
  for (int mi = 0; mi < 2; ++mi)
#pragma unroll
    for (int r = 0; r < 4; ++r) {
      int t = brow + w * 32 + mi * 16 + ((lane >> 4) << 2) + r;
#pragma unroll
      for (int ni = 0; ni < 4; ++ni) {
        int o = bcol + ni * 16 + (lane & 15);
        out[(size_t)t * DD + o] = acc[mi][ni][r] + bias[o];
      }
    }
}

// ---------------- launch ----------------
extern "C" void kernel_launch(void* const* d_in, const int* in_sizes, int n_in,
                              void* d_out, int out_size, void* d_ws, size_t ws_size,
                              hipStream_t stream) {
  const float* q  = (const float*)d_in[0];
  const float* k  = (const float*)d_in[1];
  const float* v  = (const float*)d_in[2];
  const int* pos  = (const int*)d_in[3];
  const float* wq = (const float*)d_in[4];
  const float* wk = (const float*)d_in[5];
  const float* wv = (const float*)d_in[6];
  const float* wo = (const float*)d_in[7];
  const float* wob = (const float*)d_in[8];
  float* out = (float*)d_out;
  char* ws = (char*)d_ws;

  const size_t MB = 1u << 20;
  unsigned short* XQ = (unsigned short*)(ws + 0 * MB);
  unsigned short* XK = (unsigned short*)(ws + 4 * MB);
  unsigned short* XV = (unsigned short*)(ws + 8 * MB);
  unsigned short* WQ = (unsigned short*)(ws + 12 * MB);
  unsigned short* WK = (unsigned short*)(ws + 14 * MB);
  unsigned short* WV = (unsigned short*)(ws + 16 * MB);
  unsigned short* WO = (unsigned short*)(ws + 18 * MB);
  unsigned short* QF = (unsigned short*)(ws + 20 * MB);
  unsigned short* KF = (unsigned short*)(ws + 24 * MB);
  unsigned short* VF = (unsigned short*)(ws + 28 * MB);
  unsigned short* AOb = (unsigned short*)(ws + 32 * MB);
  float* COS = (float*)(ws + 36 * MB);
  float* SIN = (float*)(ws + 36 * MB + 262144);

  hipLaunchKernelGGL(cvt_all, dim3(5376), dim3(256), 0, stream,
                     q, k, v, wq, wk, wv, wo, XQ, XK, XV, WQ, WK, WV, WO,
                     pos, COS, SIN);
  hipLaunchKernelGGL(gemm_qkv, dim3(32, 8, 3), dim3(256), 0, stream,
                     XQ, XK, XV, WQ, WK, WV, QF, KF, VF, COS, SIN);
  hipLaunchKernelGGL(attn_fa, dim3(1024), dim3(256), 0, stream, QF, KF, VF, AOb);
  hipLaunchKernelGGL(gemm_o, dim3(16, 16), dim3(256), 0, stream, AOb, WO, wob, out);
}

// Round 11
// 67.852 us; speedup vs baseline: 1.4010x; 1.0588x over previous
//
#include <hip/hip_runtime.h>
#include <hip/hip_bf16.h>
#include <stdint.h>

#define TT 2048
#define DD 1024
#define NH 16
#define DK 64

typedef __attribute__((ext_vector_type(8))) short bf16x8;
typedef __attribute__((ext_vector_type(4))) float f32x4;
typedef __attribute__((ext_vector_type(8))) unsigned short u16x8;
typedef __attribute__((ext_vector_type(4))) unsigned short u16x4;

__device__ __forceinline__ unsigned short f2bf(float f) {
  union { float f; unsigned u; } x; x.f = f;
  unsigned r = (x.u + 0x7FFFu + ((x.u >> 16) & 1u)) >> 16;
  return (unsigned short)r;
}

__device__ __forceinline__ void gload16(const void* g, void* l) {
  __builtin_amdgcn_global_load_lds(
      (const __attribute__((address_space(1))) unsigned int*)g,
      (__attribute__((address_space(3))) unsigned int*)l, 16, 0, 0);
}

// ---------------- convert f32 -> bf16  (+ fused RoPE table) ----------------
__global__ __launch_bounds__(256) void cvt_all(
    const float* __restrict__ q, const float* __restrict__ k, const float* __restrict__ v,
    const float* __restrict__ wq, const float* __restrict__ wk, const float* __restrict__ wv,
    const float* __restrict__ wo,
    unsigned short* __restrict__ oq, unsigned short* __restrict__ ok, unsigned short* __restrict__ ov,
    unsigned short* __restrict__ owq, unsigned short* __restrict__ owk, unsigned short* __restrict__ owv,
    unsigned short* __restrict__ owo,
    const int* __restrict__ pos, float* __restrict__ cosT, float* __restrict__ sinT) {
  int b = blockIdx.x;
  if (b >= 5120) {  // RoPE cos/sin table: 2048*32 entries over 256 blocks
    int idx = (b - 5120) * 256 + threadIdx.x;
    int t = idx >> 5, i = idx & 31;
    float inv = exp2f((float)i * -0.41524101186092028f);  // 10000^(-i/32)
    float ang = (float)pos[t] * inv;
    cosT[idx] = cosf(ang);
    sinT[idx] = sinf(ang);
    return;
  }
  const float* src; unsigned short* dst; int sb;
  if (b < 1024)      { src = q;  dst = oq;  sb = b; }
  else if (b < 2048) { src = k;  dst = ok;  sb = b - 1024; }
  else if (b < 3072) { src = v;  dst = ov;  sb = b - 2048; }
  else if (b < 3584) { src = wq; dst = owq; sb = b - 3072; }
  else if (b < 4096) { src = wk; dst = owk; sb = b - 3584; }
  else if (b < 4608) { src = wv; dst = owv; sb = b - 4096; }
  else               { src = wo; dst = owo; sb = b - 4608; }
  size_t i0 = (size_t)sb * 2048 + (size_t)threadIdx.x * 8;
  f32x4 a = *(const f32x4*)(src + i0);
  f32x4 c = *(const f32x4*)(src + i0 + 4);
  u16x8 r;
#pragma unroll
  for (int j = 0; j < 4; ++j) { r[j] = f2bf(a[j]); r[j + 4] = f2bf(c[j]); }
  *(u16x8*)(dst + i0) = r;
}

// ---------------- fused QKV projection + RoPE ----------------
// BM=64 x BN=128, BK=128 (8 K-iters: half the barrier drains of BK=64).
// grid (32,8,3) = 768 blocks = 3 blocks/CU. LDS 48KB/block (3 fit).
// 256B LDS rows; swizzle byte ^= (row&15)<<4 (2 lanes/bank = free).
// Outputs in MFMA FRAGMENT-NATIVE layouts (attn loads = base + lane*16).
__global__ __launch_bounds__(256) void gemm_qkv(
    const unsigned short* __restrict__ xq, const unsigned short* __restrict__ xk,
    const unsigned short* __restrict__ xv,
    const unsigned short* __restrict__ wqb, const unsigned short* __restrict__ wkb,
    const unsigned short* __restrict__ wvb,
    unsigned short* __restrict__ QF, unsigned short* __restrict__ KF,
    unsigned short* __restrict__ VF,
    const float* __restrict__ cosT, const float* __restrict__ sinT) {
  __shared__ unsigned short Ash[64 * 128];
  __shared__ unsigned short Bsh[128 * 128];
  const int z = blockIdx.z;
  const unsigned short* A = (z == 0) ? xq : (z == 1) ? xk : xv;
  const unsigned short* W = (z == 0) ? wqb : (z == 1) ? wkb : wvb;
  const int brow = blockIdx.x * 64;
  const int bcol = blockIdx.y * 128;
  const int tid = threadIdx.x;
  const int lane = tid & 63;
  const int w = tid >> 6;
  const int wr = w >> 1, wc = w & 1;
  const char* Ab = (const char*)A + (size_t)brow * (DD * 2);
  const char* Wb = (const char*)W + (size_t)bcol * (DD * 2);
  char* AshB = (char*)Ash;
  char* BshB = (char*)Bsh;
  f32x4 acc[2][4];
#pragma unroll
  for (int mi = 0; mi < 2; ++mi)
#pragma unroll
    for (int ni = 0; ni < 4; ++ni)
#pragma unroll
      for (int r = 0; r < 4; ++r) acc[mi][ni][r] = 0.0f;

  for (int k0 = 0; k0 < DD; k0 += 128) {
    __syncthreads();
#pragma unroll
    for (int it = 0; it < 4; ++it) {  // A: 64x128 bf16 = 16KB
      int c = it * 256 + tid;
      int row = c >> 4;
      int xb = (c & 15) << 4;
      int sxb = xb ^ ((row & 15) << 4);
      int ldso = (it * 256 + (tid & 192)) << 4;
      gload16(Ab + (size_t)row * (DD * 2) + k0 * 2 + sxb, AshB + ldso);
    }
#pragma unroll
    for (int it = 0; it < 8; ++it) {  // B: 128x128 bf16 = 32KB
      int c = it * 256 + tid;
      int row = c >> 4;
      int xb = (c & 15) << 4;
      int sxb = xb ^ ((row & 15) << 4);
      int ldso = (it * 256 + (tid & 192)) << 4;
      gload16(Wb + (size_t)row * (DD * 2) + k0 * 2 + sxb, BshB + ldso);
    }
    __syncthreads();
#pragma unroll
    for (int ks = 0; ks < 4; ++ks) {
      bf16x8 af[2], bfr[4];
      int colb = ks * 64 + ((lane >> 4) << 4);
#pragma unroll
      for (int mi = 0; mi < 2; ++mi) {
        int row = wr * 32 + mi * 16 + (lane & 15);
        af[mi] = *(const bf16x8*)(AshB + row * 256 + (colb ^ ((row & 15) << 4)));
      }
#pragma unroll
      for (int ni = 0; ni < 4; ++ni) {
        int row = wc * 64 + ni * 16 + (lane & 15);
        bfr[ni] = *(const bf16x8*)(BshB + row * 256 + (colb ^ ((row & 15) << 4)));
      }
#pragma unroll
      for (int mi = 0; mi < 2; ++mi)
#pragma unroll
        for (int ni = 0; ni < 4; ++ni)
          acc[mi][ni] = __builtin_amdgcn_mfma_f32_16x16x32_bf16(af[mi], bfr[ni], acc[mi][ni], 0, 0, 0);
    }
  }

  const int hcol = bcol + wc * 64;
  const int h = hcol >> 6;
  if (z == 0) {
    // Q + RoPE + scale(1/8 * log2e) -> QF fragment-native
    const float sc = 0.18033688011112042f;
#pragma unroll
    for (int mi = 0; mi < 2; ++mi) {
#pragma unroll
      for (int r = 0; r < 4; ++r) {
        int t = brow + wr * 32 + mi * 16 + ((lane >> 4) << 2) + r;
        int qw_ = t >> 5, mif = (t >> 4) & 1, r16 = t & 15;
        size_t fb = (((size_t)(h * 64 + qw_) * 2 + mif) * 2) * 1024;  // bytes, ks=0
#pragma unroll
        for (int ni = 0; ni < 2; ++ni) {
          int dl = ni * 16 + (lane & 15);  // d in [0,32)
          float cv = cosT[t * 32 + dl];
          float sv = sinT[t * 32 + dl];
          float x1 = acc[mi][ni][r];
          float x2 = acc[mi][ni + 2][r];
          size_t off = fb + (size_t)(r16 + 16 * (dl >> 3)) * 16 + (dl & 7) * 2;
          *(unsigned short*)((char*)QF + off) = f2bf((x1 * cv - x2 * sv) * sc);
          *(unsigned short*)((char*)QF + off + 1024) = f2bf((x2 * cv + x1 * sv) * sc);
        }
      }
    }
  } else if (z == 1) {
    // K + RoPE -> KF fragment-native
#pragma unroll
    for (int mi = 0; mi < 2; ++mi) {
#pragma unroll
      for (int r = 0; r < 4; ++r) {
        int t = brow + wr * 32 + mi * 16 + ((lane >> 4) << 2) + r;
        int kt = t >> 6, nif = (t >> 4) & 3, r16 = t & 15;
        size_t fb = (((size_t)(h * 32 + kt) * 2) * 4 + nif) * 1024;  // bytes, ks=0
#pragma unroll
        for (int ni = 0; ni < 2; ++ni) {
          int dl = ni * 16 + (lane & 15);
          float cv = cosT[t * 32 + dl];
          float sv = sinT[t * 32 + dl];
          float x1 = acc[mi][ni][r];
          float x2 = acc[mi][ni + 2][r];
          size_t off = fb + (size_t)(r16 + 16 * (dl >> 3)) * 16 + (dl & 7) * 2;
          *(unsigned short*)((char*)KF + off) = f2bf(x1 * cv - x2 * sv);
          *(unsigned short*)((char*)KF + off + 4096) = f2bf(x2 * cv + x1 * sv);  // ks=1
        }
      }
    }
  } else {
    // V -> VF fragment-native
#pragma unroll
    for (int mi = 0; mi < 2; ++mi) {
      int t0 = brow + wr * 32 + mi * 16 + ((lane >> 4) << 2);
      int kt = t0 >> 6, ksf = (t0 & 63) >> 5, slot = (t0 & 31) >> 3, j0 = t0 & 7;
#pragma unroll
      for (int ni = 0; ni < 4; ++ni) {
        int dh = ni * 16 + (lane & 15);
        int lanef = (dh & 15) + 16 * slot;
        size_t off = ((((size_t)(h * 32 + kt) * 2 + ksf) * 4 + ni) * 64 + lanef) * 16 + j0 * 2;
        u16x4 pk;
#pragma unroll
        for (int r = 0; r < 4; ++r) pk[r] = f2bf(acc[mi][ni][r]);
        *(u16x4*)((char*)VF + off) = pk;
      }
    }
  }
}

// ---------------- causal flash attention (unchanged, R7-verified) -----------
__global__ __launch_bounds__(256, 2) void attn_fa(
    const unsigned short* __restrict__ QF, const unsigned short* __restrict__ KF,
    const unsigned short* __restrict__ VF, unsigned short* __restrict__ AO) {
  __shared__ char LB[26624];
  __shared__ float MR[4][32];
  const int tid = threadIdx.x;
  const int lane = tid & 63;
  const int w = tid >> 6;
  const int bid = blockIdx.x;
  const int xcd = bid & 7;
  const int idx = bid >> 3;          // 128 jobs per XCD
  const int h = xcd * 2 + (idx & 1); // 2 heads pinned per XCD
  const int qw = 63 - (idx >> 1);    // biggest jobs dispatch first
  const int q0w = qw * 32;
  const int NT = (qw >> 1) + 1;
  char* PshB = LB + w * 4096;
  const char* Kb = (const char*)KF + (size_t)h * 32 * 8192;  // 8KB per k-tile
  const char* Vb = (const char*)VF + (size_t)h * 32 * 8192;

  bf16x8 qf[2][2];
  {
    const char* Qb = (const char*)QF + (size_t)(h * 64 + qw) * 4096;
#pragma unroll
    for (int mi = 0; mi < 2; ++mi)
#pragma unroll
      for (int ks = 0; ks < 2; ++ks)
        qf[mi][ks] = *(const bf16x8*)(Qb + (mi * 2 + ks) * 1024 + lane * 16);
  }

  bf16x8 vone;
#pragma unroll
  for (int j = 0; j < 8; ++j) vone[j] = (short)0x3F80;  // bf16 1.0

  f32x4 accO[2][5];  // [..][4] = row-sum l (ones-column MFMA)
  float mrow[2];
#pragma unroll
  for (int mi = 0; mi < 2; ++mi) {
    mrow[mi] = -1e30f;
#pragma unroll
    for (int ni = 0; ni < 5; ++ni)
#pragma unroll
      for (int r = 0; r < 4; ++r) accO[mi][ni][r] = 0.0f;
  }

  bf16x8 kfA[2][4], kfB[2][4], vf[2][4];
  {
    int kt0 = (w < NT) ? w : 0;
    const char* p = Kb + (size_t)kt0 * 8192 + lane * 16;
#pragma unroll
    for (int ks = 0; ks < 2; ++ks)
#pragma unroll
      for (int ni = 0; ni < 4; ++ni)
        kfA[ks][ni] = *(const bf16x8*)(p + (ks * 4 + ni) * 1024);
  }

  for (int kt = w; kt < NT; kt += 4) {
    {  // V tile: coalesced; issue early, QK+softmax hides latency
      const char* p = Vb + (size_t)kt * 8192 + lane * 16;
#pragma unroll
      for (int ks = 0; ks < 2; ++ks)
#pragma unroll
        for (int ni = 0; ni < 4; ++ni)
          vf[ks][ni] = *(const bf16x8*)(p + (ks * 4 + ni) * 1024);
    }
    f32x4 s[2][4];
#pragma unroll
    for (int mi = 0; mi < 2; ++mi)
#pragma unroll
      for (int ni = 0; ni < 4; ++ni)
#pragma unroll
        for (int r = 0; r < 4; ++r) s[mi][ni][r] = 0.0f;
    // swapped: S^T[k][q] = K-frag (A) x Q-frag (B)
    __builtin_amdgcn_s_setprio(1);
#pragma unroll
    for (int ks = 0; ks < 2; ++ks)
#pragma unroll
      for (int mi = 0; mi < 2; ++mi)
#pragma unroll
        for (int ni = 0; ni < 4; ++ni)
          s[mi][ni] = __builtin_amdgcn_mfma_f32_16x16x32_bf16(kfA[ks][ni], qf[mi][ks], s[mi][ni], 0, 0, 0);
    __builtin_amdgcn_s_setprio(0);
    if (kt + 4 < NT) {  // prefetch own next K tile
      const char* p = Kb + (size_t)(kt + 4) * 8192 + lane * 16;
#pragma unroll
      for (int ks = 0; ks < 2; ++ks)
#pragma unroll
        for (int ni = 0; ni < 4; ++ni)
          kfB[ks][ni] = *(const bf16x8*)(p + (ks * 4 + ni) * 1024);
    }

    if (kt == NT - 1) {  // diagonal tile: causal mask
#pragma unroll
      for (int mi = 0; mi < 2; ++mi) {
        int qq = q0w + mi * 16 + (lane & 15);
#pragma unroll
        for (int ni = 0; ni < 4; ++ni) {
          int kb = kt * 64 + ni * 16 + ((lane >> 4) << 2);
#pragma unroll
          for (int r = 0; r < 4; ++r)
            if (kb + r > qq) s[mi][ni][r] = -1e30f;
        }
      }
    }
    float rmx[2];
#pragma unroll
    for (int mi = 0; mi < 2; ++mi) {
      f32x4 t;
#pragma unroll
      for (int r = 0; r < 4; ++r)
        t[r] = fmaxf(fmaxf(s[mi][0][r], s[mi][1][r]), fmaxf(s[mi][2][r], s[mi][3][r]));
      float mx = fmaxf(fmaxf(t[0], t[1]), fmaxf(t[2], t[3]));
      mx = fmaxf(mx, __shfl_xor(mx, 16, 64));
      mx = fmaxf(mx, __shfl_xor(mx, 32, 64));
      rmx[mi] = mx;
    }
    bool need = (rmx[0] > mrow[0] + 8.0f) || (rmx[1] > mrow[1] + 8.0f);
    if (__any(need)) {
#pragma unroll
      for (int mi = 0; mi < 2; ++mi) {
        float mn = fmaxf(mrow[mi], rmx[mi]);
        float al = exp2f(mrow[mi] - mn);
        mrow[mi] = mn;
        float ar[4];
#pragma unroll
        for (int r = 0; r < 4; ++r) ar[r] = __shfl(al, ((lane >> 4) << 2) + r, 64);
#pragma unroll
        for (int ni = 0; ni < 5; ++ni)
#pragma unroll
          for (int r = 0; r < 4; ++r) accO[mi][ni][r] *= ar[r];
      }
    }
#pragma unroll
    for (int mi = 0; mi < 2; ++mi) {
      int row = mi * 16 + (lane & 15);
      int rbase = row * 128;
      int sw = (row & 7) << 4;
#pragma unroll
      for (int ni = 0; ni < 4; ++ni) {
        unsigned u0 = __float_as_uint(exp2f(s[mi][ni][0] - mrow[mi]));
        unsigned u1 = __float_as_uint(exp2f(s[mi][ni][1] - mrow[mi]));
        unsigned u2 = __float_as_uint(exp2f(s[mi][ni][2] - mrow[mi]));
        unsigned u3 = __float_as_uint(exp2f(s[mi][ni][3] - mrow[mi]));
        uint2 pk;
        pk.x = (u0 >> 16) | (u1 & 0xFFFF0000u);
        pk.y = (u2 >> 16) | (u3 & 0xFFFF0000u);
        int cb = ni * 32 + ((lane >> 4) << 3);
        *(uint2*)(PshB + rbase + (cb ^ sw)) = pk;
      }
    }
    asm volatile("" ::: "memory");
    __builtin_amdgcn_s_setprio(1);
#pragma unroll
    for (int ks = 0; ks < 2; ++ks) {
      bf16x8 pf[2];
#pragma unroll
      for (int mi = 0; mi < 2; ++mi) {
        int row = mi * 16 + (lane & 15);
        int cb = ks * 64 + ((lane >> 4) << 4);
        pf[mi] = *(const bf16x8*)(PshB + row * 128 + (cb ^ ((row & 7) << 4)));
      }
#pragma unroll
      for (int mi = 0; mi < 2; ++mi) {
#pragma unroll
        for (int ni = 0; ni < 4; ++ni)
          accO[mi][ni] = __builtin_amdgcn_mfma_f32_16x16x32_bf16(pf[mi], vf[ks][ni], accO[mi][ni], 0, 0, 0);
        accO[mi][4] = __builtin_amdgcn_mfma_f32_16x16x32_bf16(pf[mi], vone, accO[mi][4], 0, 0, 0);
      }
    }
    __builtin_amdgcn_s_setprio(0);
#pragma unroll
    for (int ks = 0; ks < 2; ++ks)
#pragma unroll
      for (int ni = 0; ni < 4; ++ni) kfA[ks][ni] = kfB[ks][ni];
  }

  __syncthreads();  // all waves done with P buffers; LB becomes MO partials
  if ((lane >> 4) == 0) {
    MR[w][lane] = mrow[0];
    MR[w][16 + lane] = mrow[1];
  }
  if (w > 0) {
    float* MOw = (float*)LB + (size_t)(w - 1) * 32 * 68;
#pragma unroll
    for (int mi = 0; mi < 2; ++mi) {
#pragma unroll
      for (int r = 0; r < 4; ++r) {
        int rq = mi * 16 + ((lane >> 4) << 2) + r;
#pragma unroll
        for (int ni = 0; ni < 4; ++ni)
          MOw[rq * 68 + ni * 16 + (lane & 15)] = accO[mi][ni][r];
        if ((lane & 15) == 0) MOw[rq * 68 + 64] = accO[mi][4][r];
      }
    }
  }
  __syncthreads();
  if (w == 0) {
    const float* MOp = (const float*)LB;
#pragma unroll
    for (int mi = 0; mi < 2; ++mi) {
#pragma unroll
      for (int r = 0; r < 4; ++r) {
        int rq = mi * 16 + ((lane >> 4) << 2) + r;
        float m0 = MR[0][rq], m1 = MR[1][rq], m2 = MR[2][rq], m3 = MR[3][rq];
        float M = fmaxf(fmaxf(m0, m1), fmaxf(m2, m3));
        float a0 = exp2f(m0 - M), a1 = exp2f(m1 - M);
        float a2 = exp2f(m2 - M), a3 = exp2f(m3 - M);
        float denom = a0 * accO[mi][4][r] + a1 * MOp[(0 * 32 + rq) * 68 + 64] +
                      a2 * MOp[(1 * 32 + rq) * 68 + 64] + a3 * MOp[(2 * 32 + rq) * 68 + 64];
        float inv = 1.0f / denom;
        int t = q0w + rq;
#pragma unroll
        for (int ni = 0; ni < 4; ++ni) {
          int dh = ni * 16 + (lane & 15);
          float o = a0 * accO[mi][ni][r] + a1 * MOp[(0 * 32 + rq) * 68 + dh] +
                    a2 * MOp[(1 * 32 + rq) * 68 + dh] + a3 * MOp[(2 * 32 + rq) * 68 + dh];
          AO[(size_t)t * DD + h * DK + dh] = f2bf(o * inv);
        }
      }
    }
  }
}

// ---------------- output projection + bias (f32 out) ----------------
// BM=64 x BN=64, BK=128; grid (32,16) = 512 blocks = 2 blocks/CU.
// 4 waves: each 32x32 (wr=w>>1, wc=w&1), acc[2][2].
__global__ __launch_bounds__(256) void gemm_o(
    const unsigned short* __restrict__ A, const unsigned short* __restrict__ W,
    const float* __restrict__ bias, float* __restrict__ out) {
  __shared__ unsigned short Ash[64 * 128];
  __shared__ unsigned short Bsh[64 * 128];
  const int brow = blockIdx.x * 64;
  const int bcol = blockIdx.y * 64;
  const int tid = threadIdx.x;
  const int lane = tid & 63;
  const int w = tid >> 6;
  const int wr = w >> 1, wc = w & 1;
  const char* Ab = (const char*)A + (size_t)brow * (DD * 2);
  const char* Wb = (const char*)W + (size_t)bcol * (DD * 2);
  char* AshB = (char*)Ash;
  char* BshB = (char*)Bsh;
  f32x4 acc[2][2];
#pragma unroll
  for (int mi = 0; mi < 2; ++mi)
#pragma unroll
    for (int ni = 0; ni < 2; ++ni)
#pragma unroll
      for (int r = 0; r < 4; ++r) acc[mi][ni][r] = 0.0f;

  for (int k0 = 0; k0 < DD; k0 += 128) {
    __syncthreads();
#pragma unroll
    for (int it = 0; it < 4; ++it) {  // A: 64x128 bf16 = 16KB
      int c = it * 256 + tid;
      int row = c >> 4;
      int xb = (c & 15) << 4;
      int sxb = xb ^ ((row & 15) << 4);
      int ldso = (it * 256 + (tid & 192)) << 4;
      gload16(Ab + (size_t)row * (DD * 2) + k0 * 2 + sxb, AshB + ldso);
    }
#pragma unroll
    for (int it = 0; it < 4; ++it) {  // W: 64x128 bf16 = 16KB
      int c = it * 256 + tid;
      int row = c >> 4;
      int xb = (c & 15) << 4;
      int sxb = xb ^ ((row & 15) << 4);
      int ldso = (it * 256 + (tid & 192)) << 4;
      gload16(Wb + (size_t)row * (DD * 2) + k0 * 2 + sxb, BshB + ldso);
    }
    __syncthreads();
#pragma unroll
    for (int ks = 0; ks < 4; ++ks) {
      bf16x8 af[2], bfr[2];
      int colb = ks * 64 + ((lane >> 4) << 4);
#pragma unroll
      for (int mi = 0; mi < 2; ++mi) {
        int row = wr * 32 + mi * 16 + (lane & 15);
        af[mi] = *(const bf16x8*)(AshB + row * 256 + (colb ^ ((row & 15) << 4)));
      }
#pragma unroll
      for (int ni = 0; ni < 2; ++ni) {
        int row = wc * 32 + ni * 16 + (lane & 15);
        bfr[ni] = *(const bf16x8*)(BshB + row * 256 + (colb ^ ((row & 15) << 4)));
      }
#pragma unroll
      for (int mi = 0; mi < 2; ++mi)
#pragma unroll
        for (int ni = 0; ni < 2; ++ni)
          acc[mi][ni] = __builtin_amdgcn_mfma_f32_16x16x32_bf16(af[mi], bfr[ni], acc[mi][ni], 0, 0, 0);
    }
  }
#pragma unroll
  for (int mi = 0; mi < 2; ++mi)
#pragma unroll
    for (int r = 0; r < 4; ++r) {
      int t = brow + wr * 32 + mi * 16 + ((lane >> 4) << 2) + r;
#pragma unroll
      for (int ni = 0; ni < 2; ++ni) {
        int o = bcol + wc * 32 + ni * 16 + (lane & 15);
        out[(size_t)t * DD + o] = acc[mi][ni][r] + bias[o];
      }
    }
}

// ---------------- launch ----------------
extern "C" void kernel_launch(void* const* d_in, const int* in_sizes, int n_in,
                              void* d_out, int out_size, void* d_ws, size_t ws_size,
                              hipStream_t stream) {
  const float* q  = (const float*)d_in[0];
  const float* k  = (const float*)d_in[1];
  const float* v  = (const float*)d_in[2];
  const int* pos  = (const int*)d_in[3];
  const float* wq = (const float*)d_in[4];
  const float* wk = (const float*)d_in[5];
  const float* wv = (const float*)d_in[6];
  const float* wo = (const float*)d_in[7];
  const float* wob = (const float*)d_in[8];
  float* out = (float*)d_out;
  char* ws = (char*)d_ws;

  const size_t MB = 1u << 20;
  unsigned short* XQ = (unsigned short*)(ws + 0 * MB);
  unsigned short* XK = (unsigned short*)(ws + 4 * MB);
  unsigned short* XV = (unsigned short*)(ws + 8 * MB);
  unsigned short* WQ = (unsigned short*)(ws + 12 * MB);
  unsigned short* WK = (unsigned short*)(ws + 14 * MB);
  unsigned short* WV = (unsigned short*)(ws + 16 * MB);
  unsigned short* WO = (unsigned short*)(ws + 18 * MB);
  unsigned short* QF = (unsigned short*)(ws + 20 * MB);
  unsigned short* KF = (unsigned short*)(ws + 24 * MB);
  unsigned short* VF = (unsigned short*)(ws + 28 * MB);
  unsigned short* AOb = (unsigned short*)(ws + 32 * MB);
  float* COS = (float*)(ws + 36 * MB);
  float* SIN = (float*)(ws + 36 * MB + 262144);

  hipLaunchKernelGGL(cvt_all, dim3(5376), dim3(256), 0, stream,
                     q, k, v, wq, wk, wv, wo, XQ, XK, XV, WQ, WK, WV, WO,
                     pos, COS, SIN);
  hipLaunchKernelGGL(gemm_qkv, dim3(32, 8, 3), dim3(256), 0, stream,
                     XQ, XK, XV, WQ, WK, WV, QF, KF, VF, COS, SIN);
  hipLaunchKernelGGL(attn_fa, dim3(1024), dim3(256), 0, stream, QF, KF, VF, AOb);
  hipLaunchKernelGGL(gemm_o, dim3(32, 16), dim3(256), 0, stream, AOb, WO, wob, out);
}